// Round 11
// baseline (246.175 us; speedup 1.0000x reference)
//
#include <hip/hip_runtime.h>

#define B_   8
#define N_   4096
#define S_   1024
#define M_   2048
#define D1_  128
#define D2_  256
#define CIN_ 388
#define KP0  416          // K of layer0, padded to 13*32
#define K12  512          // K of layers 1,2
#define J_   (B_ * N_)    // 32768
#define SS   (S_ / 8)     // 128 candidates per eighth
#define MM   (M_ / 8)     // 256 keypoints per eighth
#define NJB  256          // j-blocks per GEMM (J/128)
#define BN_EPS 1e-5f

typedef __bf16 bf16x8 __attribute__((ext_vector_type(8)));
typedef float  f32x4  __attribute__((ext_vector_type(4)));
typedef unsigned short ushort_t;

__device__ __forceinline__ float mulrn(float a, float b) { return __fmul_rn(a, b); }
__device__ __forceinline__ float addrn(float a, float b) { return __fadd_rn(a, b); }
__device__ __forceinline__ float subrn(float a, float b) { return __fsub_rn(a, b); }
__device__ __forceinline__ float norm3(float x, float y, float z) {
    return addrn(addrn(mulrn(x, x), mulrn(y, y)), mulrn(z, z));
}
__device__ __forceinline__ ushort_t f2bf(float f) {  // RNE
    unsigned int u = __float_as_uint(f);
    return (ushort_t)((u + 0x7FFFu + ((u >> 16) & 1u)) >> 16);
}
__device__ __forceinline__ float bf2f(ushort_t u) {
    return __uint_as_float(((unsigned int)u) << 16);
}
// lexicographic (d, idx) compare — reproduces stable top-k tie-breaking
__device__ __forceinline__ bool plt(float da, int ia, float db, int ib) {
    return (da < db) || (da == db && ia < ib);
}

// ---------------------------------------------------------------------------
// points2 [B][D2][S] -> p2t [B][S][D2]  (fp32, feeds exact interp math)
__global__ __launch_bounds__(256) void k_transpose_p2(const float* __restrict__ p2,
                                                      float* __restrict__ p2t) {
    __shared__ float tile[32][33];
    int b = blockIdx.z;
    int s0 = blockIdx.x * 32, c0 = blockIdx.y * 32;
    int tx = threadIdx.x, ty = threadIdx.y;  // 32 x 8
#pragma unroll
    for (int i = 0; i < 4; i++)
        tile[ty + i * 8][tx] = p2[(size_t)b * D2_ * S_ + (size_t)(c0 + ty + i * 8) * S_ + s0 + tx];
    __syncthreads();
#pragma unroll
    for (int i = 0; i < 4; i++)
        p2t[(size_t)b * S_ * D2_ + (size_t)(s0 + ty + i * 8) * D2_ + c0 + tx] = tile[tx][ty + i * 8];
}

// ---------------------------------------------------------------------------
// W [O][C] fp32 -> Wb [O][Kp] bf16, zero-padded cols (already k-contiguous)
__global__ __launch_bounds__(256) void k_prep_w(const float* __restrict__ W,
                                                ushort_t* __restrict__ Wb, int O, int C, int Kp) {
    int i = blockIdx.x * 256 + threadIdx.x;
    if (i >= O * Kp) return;
    int o = i / Kp, k = i - o * Kp;
    Wb[i] = (k < C) ? f2bf(W[(size_t)o * C + k]) : (ushort_t)0;
}

// ---------------------------------------------------------------------------
// points1 [B][D1][N] fp32 -> XT[j][0:128] bf16 (LDS tile transpose)
__global__ __launch_bounds__(256) void k_p1t(const float* __restrict__ p1,
                                             ushort_t* __restrict__ XT) {
    __shared__ ushort_t tile[32][132];
    int b = blockIdx.y;
    int n0 = blockIdx.x * 32;
    int t = threadIdx.x;

    {
        int nl = t & 31, cq = t >> 5;
#pragma unroll
        for (int k = 0; k < 16; k++) {
            int c = cq * 16 + k;
            tile[nl][c] = f2bf(p1[(size_t)b * D1_ * N_ + (size_t)c * N_ + n0 + nl]);
        }
    }
    __syncthreads();
    {
        int nl = t >> 3, sub = t & 7;
        size_t j = (size_t)b * N_ + n0 + nl;
#pragma unroll
        for (int k = 0; k < 4; k++) {
            int chunk = k * 8 + sub;
            *(uint2*)&XT[j * KP0 + chunk * 4] = *(const uint2*)&tile[nl][chunk * 4];
        }
    }
}

// ---------------------------------------------------------------------------
// Scan phase: one THREAD per query, one candidate-EIGHTH per block.
__global__ __launch_bounds__(512) void k_scan(const float* __restrict__ xyz1,
                                              const float* __restrict__ xyz2,
                                              const float* __restrict__ feature,
                                              float* __restrict__ outp) {
    __shared__ float4 sL[SS];
    __shared__ float4 fL[MM];
    int tid = threadIdx.x;
    int e = blockIdx.y;
    int j = blockIdx.x * 512 + tid;
    int b = blockIdx.x >> 3;           // 8 blocks.x per batch (4096/512)
    int n = j & (N_ - 1);

    for (int i = tid; i < SS + MM; i += 512) {
        if (i < SS) {
            int s = e * SS + i;
            float x = xyz2[(size_t)b * 3 * S_ + s];
            float y = xyz2[(size_t)b * 3 * S_ + S_ + s];
            float z = xyz2[(size_t)b * 3 * S_ + 2 * S_ + s];
            sL[i] = make_float4(x, y, z, norm3(x, y, z));
        } else {
            int m = e * MM + (i - SS);
            float4 f = *(const float4*)(feature + (size_t)b * M_ * 4 + (size_t)m * 4);
            fL[i - SS] = make_float4(f.y, f.z, f.w, norm3(f.y, f.z, f.w));
        }
    }
    __syncthreads();

    float qx = xyz1[(size_t)b * 3 * N_ + n];
    float qy = xyz1[(size_t)b * 3 * N_ + N_ + n];
    float qz = xyz1[(size_t)b * 3 * N_ + 2 * N_ + n];
    float qn = norm3(qx, qy, qz);

    float d0 = 1e30f, d1 = 1e30f, d2 = 1e30f;
    int i0 = 0, i1 = 0, i2 = 0;
#pragma unroll 4
    for (int i = 0; i < SS; i++) {
        float4 c = sL[i];
        float dot = addrn(addrn(mulrn(qx, c.x), mulrn(qy, c.y)), mulrn(qz, c.z));
        float d = subrn(addrn(qn, c.w), mulrn(2.0f, dot));
        int s = e * SS + i;
        bool l0 = d < d0, l1 = d < d1, l2 = d < d2;
        d2 = l1 ? d1 : (l2 ? d : d2);  i2 = l1 ? i1 : (l2 ? s : i2);
        d1 = l0 ? d0 : (l1 ? d : d1);  i1 = l0 ? i0 : (l1 ? s : i1);
        d0 = l0 ? d  : d0;             i0 = l0 ? s  : i0;
    }

    float dm = 1e30f; int im = 0;
#pragma unroll 4
    for (int i = 0; i < MM; i++) {
        float4 c = fL[i];
        float dot = addrn(addrn(mulrn(qx, c.x), mulrn(qy, c.y)), mulrn(qz, c.z));
        float d = subrn(addrn(qn, c.w), mulrn(2.0f, dot));
        if (d < dm) { dm = d; im = e * MM + i; }
    }

    float* o = outp + ((size_t)j * 8 + e) * 8;
    float4 v0 = {d0, d1, d2, dm};
    float4 v1 = {__int_as_float(i0), __int_as_float(i1), __int_as_float(i2), __int_as_float(im)};
    *(float4*)o = v0;
    *(float4*)(o + 4) = v1;
}

// ---------------------------------------------------------------------------
// Merge + assembly: one WAVE per query; 3-step lexicographic butterfly merge.
__global__ __launch_bounds__(256) void k_nn2(const float* __restrict__ feature,
                                             const float* __restrict__ p2t,
                                             const float* __restrict__ outp,
                                             ushort_t* __restrict__ XT) {
    int bq = blockIdx.y;
    int wid = threadIdx.x >> 6;
    int l = threadIdx.x & 63;
    int n = blockIdx.x * 4 + wid;
    size_t j = (size_t)bq * N_ + n;
    const float* fb = feature + (size_t)bq * M_ * 4;

    float d0 = 1e30f, d1 = 1e30f, d2 = 1e30f, dm = 1e30f;
    int i0 = 0, i1 = 0, i2 = 0, im = 0;
    if (l < 8) {
        const float* o = outp + (j * 8 + l) * 8;
        float4 a = *(const float4*)o;
        float4 bi = *(const float4*)(o + 4);
        d0 = a.x; d1 = a.y; d2 = a.z; dm = a.w;
        i0 = __float_as_int(bi.x); i1 = __float_as_int(bi.y);
        i2 = __float_as_int(bi.z); im = __float_as_int(bi.w);
    }

#pragma unroll
    for (int off = 1; off < 8; off <<= 1) {
        float e0 = __shfl_xor(d0, off), e1 = __shfl_xor(d1, off), e2 = __shfl_xor(d2, off);
        int   f0 = __shfl_xor(i0, off), f1 = __shfl_xor(i1, off), f2 = __shfl_xor(i2, off);
        bool c0 = plt(e0, f0, d0, i0);
        float m0d = c0 ? e0 : d0; int m0i = c0 ? f0 : i0;
        float x0d = c0 ? d0 : e0; int x0i = c0 ? i0 : f0;
        bool c1 = plt(e1, f1, d1, i1);
        float n1d = c1 ? e1 : d1; int n1i = c1 ? f1 : i1;
        float z1d = c1 ? d1 : e1; int z1i = c1 ? i1 : f1;
        bool c2 = plt(e2, f2, d2, i2);
        float w2d = c2 ? e2 : d2; int w2i = c2 ? f2 : i2;
        bool c3 = plt(n1d, n1i, x0d, x0i);
        float r1d = c3 ? n1d : x0d; int r1i = c3 ? n1i : x0i;
        float t2d = c3 ? x0d : n1d; int t2i = c3 ? x0i : n1i;
        bool c4 = plt(t2d, t2i, z1d, z1i);
        float u2d = c4 ? t2d : z1d; int u2i = c4 ? t2i : z1i;
        bool c5 = plt(w2d, w2i, u2d, u2i);
        float r2d = c5 ? w2d : u2d; int r2i = c5 ? w2i : u2i;
        d0 = m0d; i0 = m0i; d1 = r1d; i1 = r1i; d2 = r2d; i2 = r2i;

        float ed = __shfl_xor(dm, off); int ei = __shfl_xor(im, off);
        if (plt(ed, ei, dm, im)) { dm = ed; im = ei; }
    }

    d0 = __shfl(d0, 0); d1 = __shfl(d1, 0); d2 = __shfl(d2, 0);
    i0 = __shfl(i0, 0); i1 = __shfl(i1, 0); i2 = __shfl(i2, 0);
    im = __shfl(im, 0);

    float w0 = 1.0f / addrn(d0, 1e-8f);
    float w1 = 1.0f / addrn(d1, 1e-8f);
    float w2 = 1.0f / addrn(d2, 1e-8f);
    float wsum = addrn(addrn(w0, w1), w2);
    w0 = w0 / wsum; w1 = w1 / wsum; w2 = w2 / wsum;

    ushort_t* xr = XT + j * KP0;
    const float* r0 = p2t + (size_t)bq * S_ * D2_ + (size_t)i0 * D2_;
    const float* r1 = p2t + (size_t)bq * S_ * D2_ + (size_t)i1 * D2_;
    const float* r2 = p2t + (size_t)bq * S_ * D2_ + (size_t)i2 * D2_;
    {
        int c = l * 4;
        float4 a = *(const float4*)(r0 + c);
        float4 bb = *(const float4*)(r1 + c);
        float4 cc = *(const float4*)(r2 + c);
        ushort_t tmp[4];
        tmp[0] = f2bf(addrn(addrn(mulrn(a.x, w0), mulrn(bb.x, w1)), mulrn(cc.x, w2)));
        tmp[1] = f2bf(addrn(addrn(mulrn(a.y, w0), mulrn(bb.y, w1)), mulrn(cc.y, w2)));
        tmp[2] = f2bf(addrn(addrn(mulrn(a.z, w0), mulrn(bb.z, w1)), mulrn(cc.z, w2)));
        tmp[3] = f2bf(addrn(addrn(mulrn(a.w, w0), mulrn(bb.w, w1)), mulrn(cc.w, w2)));
        *(uint2*)&xr[D1_ + c] = *(uint2*)tmp;
    }
    if (l < 8) {
        uint2 v = {0u, 0u};
        if (l == 0) {
            float4 nf = *(const float4*)(fb + (size_t)im * 4);
            ushort_t tmp[4] = {f2bf(nf.x), f2bf(nf.y), f2bf(nf.z), f2bf(nf.w)};
            v = *(uint2*)tmp;
        }
        *(uint2*)&xr[384 + l * 4] = v;
    }
}

// ---------------------------------------------------------------------------
// bf16 MFMA GEMM: T[j][o] = X[j][:]·W[o][:] + bias[o]. BN stats go to
// per-block partial arrays psumS/psumQ[jb][o] via plain coalesced stores —
// NO device atomics (256-way same-address atomic serialization was the
// suspected fixed per-block cost). Triple-buffered LDS, prefetch distance 2,
// counted s_waitcnt vmcnt(4) + raw s_barrier. Coalesced C-write via LDS
// bounce tile [128][136]. XCD-aware 1-D grid swizzle.
__global__ __launch_bounds__(256) void k_gemm(const ushort_t* __restrict__ Xb,
                                              const ushort_t* __restrict__ Wb,
                                              const float* __restrict__ bias,
                                              ushort_t* __restrict__ T,
                                              float* __restrict__ psumS,
                                              float* __restrict__ psumQ,
                                              int Kt, int Nout) {
    // 3 buffers x 16 KB (sA 8KB | sB 8KB) = 49152 B; stats 2 KB after.
    __shared__ __align__(16) char smem[51200];
    ushort_t* cb = (ushort_t*)smem;                    // bounce: 34816 B (aliases bufs)
    float* redS = (float*)(smem + 49152);              // 1 KB
    float* redQ = (float*)(smem + 50176);              // 1 KB

    int tid = threadIdx.x;
    int l = tid & 63;
    int w = tid >> 6;
    int wr = w >> 1, wc = w & 1;

    // XCD-aware bijective swizzle (grid = 256 * nY blocks, 1-D)
    int bid = blockIdx.x;
    int jb = (bid & 7) + (((bid >> 3) & 31) << 3);   // 0..255
    int ob = bid >> 8;
    int j0 = jb * 128, o0 = ob * 128;

    f32x4 acc[4][4] = {};
    int nt = Kt >> 5;

    auto stage = [&](int buf, int kt) {
        int k0 = kt << 5;
        ushort_t* base = (ushort_t*)(smem + buf * 16384);
#pragma unroll
        for (int e = 0; e < 2; ++e) {
            int i = e * 256 + tid;
            int row = i >> 2;
            int g = (i & 3) ^ ((row >> 1) & 3);   // pre-swizzled source chunk
            const ushort_t* ga = Xb + (size_t)(j0 + row) * Kt + k0 + g * 8;
            __builtin_amdgcn_global_load_lds(
                (const __attribute__((address_space(1))) void*)ga,
                (__attribute__((address_space(3))) void*)&base[i * 8], 16, 0, 0);
            const ushort_t* gb = Wb + (size_t)(o0 + row) * Kt + k0 + g * 8;
            __builtin_amdgcn_global_load_lds(
                (const __attribute__((address_space(1))) void*)gb,
                (__attribute__((address_space(3))) void*)&base[4096 + i * 8], 16, 0, 0);
        }
    };

    // prologue: 2 tiles in flight, wait only the first (vmcnt(4))
    stage(0, 0);
    stage(1, 1);
    asm volatile("s_waitcnt vmcnt(4)" ::: "memory");
    __builtin_amdgcn_s_barrier();

    for (int t = 0; t < nt; ++t) {
        if (t + 2 < nt) stage((t + 2) % 3, t + 2);

        ushort_t* base = (ushort_t*)(smem + (t % 3) * 16384);
        bf16x8 av[4], bv[4];
#pragma unroll
        for (int mi = 0; mi < 4; ++mi) {
            int r = wr * 64 + mi * 16 + (l & 15);
            int sl = (l >> 4) ^ ((r >> 1) & 3);
            av[mi] = *(const bf16x8*)&base[r * 32 + sl * 8];
        }
#pragma unroll
        for (int ni = 0; ni < 4; ++ni) {
            int r = wc * 64 + ni * 16 + (l & 15);
            int sl = (l >> 4) ^ ((r >> 1) & 3);
            bv[ni] = *(const bf16x8*)&base[4096 + r * 32 + sl * 8];
        }
#pragma unroll
        for (int mi = 0; mi < 4; ++mi)
#pragma unroll
            for (int ni = 0; ni < 4; ++ni)
                acc[mi][ni] = __builtin_amdgcn_mfma_f32_16x16x32_bf16(av[mi], bv[ni],
                                                                      acc[mi][ni], 0, 0, 0);
        // end-of-iter: need stage(t+1) complete; stage(t+2)'s 4 loads may fly.
        if (t + 2 < nt)      asm volatile("s_waitcnt vmcnt(4)" ::: "memory");
        else if (t + 1 < nt) asm volatile("s_waitcnt vmcnt(0)" ::: "memory");
        __builtin_amdgcn_s_barrier();
    }

    // ---- epilogue: stats from regs + bounce acc -> LDS -> coalesced stores
    float csum[4], csq[4];
#pragma unroll
    for (int ni = 0; ni < 4; ++ni) { csum[ni] = 0.f; csq[ni] = 0.f; }

#pragma unroll
    for (int ni = 0; ni < 4; ++ni) {
        int oc = wc * 64 + ni * 16 + (l & 15);
        float bi = bias[o0 + oc];
#pragma unroll
        for (int mi = 0; mi < 4; ++mi) {
            int jr = wr * 64 + mi * 16 + (l >> 4) * 4;
#pragma unroll
            for (int r = 0; r < 4; ++r) {
                float v = acc[mi][ni][r] + bi;
                csum[ni] += v;
                csq[ni] += v * v;
                cb[(jr + r) * 136 + oc] = f2bf(v);
            }
        }
    }

#pragma unroll
    for (int ni = 0; ni < 4; ++ni) {
        float s = csum[ni], q = csq[ni];
        s += __shfl_xor(s, 16); s += __shfl_xor(s, 32);
        q += __shfl_xor(q, 16); q += __shfl_xor(q, 32);
        if ((l & 48) == 0) {
            int oc = wc * 64 + ni * 16 + (l & 15);
            redS[oc * 2 + wr] = s;
            redQ[oc * 2 + wr] = q;
        }
    }
    __syncthreads();

    if (tid < 128) {
        psumS[(size_t)jb * Nout + o0 + tid] = redS[tid * 2] + redS[tid * 2 + 1];
        psumQ[(size_t)jb * Nout + o0 + tid] = redQ[tid * 2] + redQ[tid * 2 + 1];
    }
#pragma unroll
    for (int p = 0; p < 8; ++p) {
        int idx = p * 256 + tid;
        int jr = idx >> 4, oc8 = (idx & 15) * 8;
        uint4 v = *(const uint4*)&cb[jr * 136 + oc8];
        *(uint4*)&T[(size_t)(j0 + jr) * Nout + o0 + oc8] = v;
    }
}

// ---------------------------------------------------------------------------
// Reduce per-block partials -> BN affine (a, s): y = a*x + s
__global__ void k_affine(const float* __restrict__ pS, const float* __restrict__ pQ,
                         const float* __restrict__ g, const float* __restrict__ be,
                         float* __restrict__ A, float* __restrict__ S, int C) {
    int o = blockIdx.x * 256 + threadIdx.x;
    if (o >= C) return;
    float s = 0.f, q = 0.f;
    for (int jb = 0; jb < NJB; jb++) {
        s += pS[(size_t)jb * C + o];
        q += pQ[(size_t)jb * C + o];
    }
    float mean = s / (float)J_;
    float var = q / (float)J_ - mean * mean;
    float a = g[o] * rsqrtf(var + BN_EPS);
    A[o] = a;
    S[o] = be[o] - a * mean;
}

// ---------------------------------------------------------------------------
// In-place BN+ReLU on T [J][512] bf16 (channel = col = idx & 511)
__global__ __launch_bounds__(256) void k_norm(ushort_t* __restrict__ T,
                                              const float* __restrict__ A,
                                              const float* __restrict__ S) {
    size_t idx = ((size_t)blockIdx.x * 256 + threadIdx.x) * 8;
    int o = (int)(idx & 511);
    uint4 v = *(uint4*)&T[idx];
    ushort_t* pu = (ushort_t*)&v;
#pragma unroll
    for (int i = 0; i < 8; i++) {
        float f = bf2f(pu[i]);
        f = fmaxf(A[o + i] * f + S[o + i], 0.f);
        pu[i] = f2bf(f);
    }
    *(uint4*)&T[idx] = v;
}

// ---------------------------------------------------------------------------
// T2 [J][256] bf16 + BN affine + ReLU -> out [B][256][N] fp32 (transpose)
__global__ __launch_bounds__(256) void k_final(const ushort_t* __restrict__ T2,
                                               const float* __restrict__ A,
                                               const float* __restrict__ S,
                                               float* __restrict__ out) {
    __shared__ float tile[64][65];
    int tid = threadIdx.x;
    int jb = blockIdx.z * N_ + blockIdx.x * 64;
    int o0 = blockIdx.y * 64;

    int r = tid >> 2, cq = (tid & 3) * 16;
    uint4 v = *(const uint4*)&T2[(size_t)(jb + r) * 256 + o0 + cq];
    ushort_t* pu = (ushort_t*)&v;
#pragma unroll
    for (int i = 0; i < 8; i++) {
        int o = o0 + cq + i;
        tile[r][cq + i] = fmaxf(A[o] * bf2f(pu[i]) + S[o], 0.f);
    }
    uint4 v2 = *(const uint4*)&T2[(size_t)(jb + r) * 256 + o0 + cq + 8];
    pu = (ushort_t*)&v2;
#pragma unroll
    for (int i = 0; i < 8; i++) {
        int o = o0 + cq + 8 + i;
        tile[r][cq + 8 + i] = fmaxf(A[o] * bf2f(pu[i]) + S[o], 0.f);
    }
    __syncthreads();

    int ro = tid >> 2, jq = (tid & 3) * 16;
    float* orow = out + ((size_t)blockIdx.z * 256 + o0 + ro) * N_ + blockIdx.x * 64 + jq;
#pragma unroll
    for (int h = 0; h < 4; h++) {
        float4 ov = {tile[jq + h * 4 + 0][ro], tile[jq + h * 4 + 1][ro],
                     tile[jq + h * 4 + 2][ro], tile[jq + h * 4 + 3][ro]};
        *(float4*)(orow + h * 4) = ov;
    }
}

// ---------------------------------------------------------------------------
extern "C" void kernel_launch(void* const* d_in, const int* in_sizes, int n_in,
                              void* d_out, int out_size, void* d_ws, size_t ws_size,
                              hipStream_t stream) {
    (void)in_sizes; (void)n_in; (void)out_size; (void)ws_size;
    const float* xyz1    = (const float*)d_in[0];
    const float* xyz2    = (const float*)d_in[1];
    const float* points1 = (const float*)d_in[2];
    const float* points2 = (const float*)d_in[3];
    const float* feature = (const float*)d_in[4];
    const float* W0 = (const float*)d_in[5];
    const float* b0 = (const float*)d_in[6];
    const float* g0 = (const float*)d_in[7];
    const float* be0 = (const float*)d_in[8];
    const float* W1 = (const float*)d_in[9];
    const float* b1 = (const float*)d_in[10];
    const float* g1 = (const float*)d_in[11];
    const float* be1 = (const float*)d_in[12];
    const float* W2 = (const float*)d_in[13];
    const float* b2 = (const float*)d_in[14];
    const float* g2 = (const float*)d_in[15];
    const float* be2 = (const float*)d_in[16];

    char* ws = (char*)d_ws;
    size_t off = 0;
    auto carve = [&](size_t bytes) { char* p = ws + off; off += (bytes + 255) & ~(size_t)255; return p; };

    ushort_t* XT  = (ushort_t*)carve((size_t)J_ * KP0 * 2);
    ushort_t* T0  = (ushort_t*)carve((size_t)J_ * 512 * 2);
    ushort_t* T1  = (ushort_t*)carve((size_t)J_ * 512 * 2);
    ushort_t* T2  = (ushort_t*)carve((size_t)J_ * 256 * 2);
    float*    p2t = (float*)carve((size_t)B_ * S_ * D2_ * 4);
    float*    nnp = (float*)carve((size_t)J_ * 64 * 4);
    ushort_t* Wb0 = (ushort_t*)carve((size_t)512 * KP0 * 2);
    ushort_t* Wb1 = (ushort_t*)carve((size_t)512 * K12 * 2);
    ushort_t* Wb2 = (ushort_t*)carve((size_t)256 * K12 * 2);
    float*    pS  = (float*)carve((size_t)NJB * 512 * 4);   // per-block partial sums
    float*    pQ  = (float*)carve((size_t)NJB * 512 * 4);   // per-block partial sumsq
    float*    af  = (float*)carve(2560 * 4);
    float *A0 = af, *S0 = af + 512, *A1 = af + 1024, *S1 = af + 1536, *A2 = af + 2048, *S2 = af + 2304;

    k_prep_w<<<dim3((512 * KP0 + 255) / 256), 256, 0, stream>>>(W0, Wb0, 512, CIN_, KP0);
    k_prep_w<<<dim3((512 * K12 + 255) / 256), 256, 0, stream>>>(W1, Wb1, 512, 512, K12);
    k_prep_w<<<dim3((512 * 256 + 255) / 256), 256, 0, stream>>>(W2, Wb2, 256, 512, K12);
    k_transpose_p2<<<dim3(S_ / 32, D2_ / 32, B_), dim3(32, 8), 0, stream>>>(points2, p2t);
    k_p1t<<<dim3(N_ / 32, B_), 256, 0, stream>>>(points1, XT);
    k_scan<<<dim3(J_ / 512, 8), 512, 0, stream>>>(xyz1, xyz2, feature, nnp);
    k_nn2<<<dim3(N_ / 4, B_), 256, 0, stream>>>(feature, p2t, nnp, XT);

    k_gemm<<<dim3(256 * 4), 256, 0, stream>>>(XT, Wb0, b0, T0, pS, pQ, KP0, 512);
    k_affine<<<dim3(2), 256, 0, stream>>>(pS, pQ, g0, be0, A0, S0, 512);
    k_norm<<<dim3((int)((size_t)J_ * 512 / 8 / 256)), 256, 0, stream>>>(T0, A0, S0);

    k_gemm<<<dim3(256 * 4), 256, 0, stream>>>(T0, Wb1, b1, T1, pS, pQ, K12, 512);
    k_affine<<<dim3(2), 256, 0, stream>>>(pS, pQ, g1, be1, A1, S1, 512);
    k_norm<<<dim3((int)((size_t)J_ * 512 / 8 / 256)), 256, 0, stream>>>(T1, A1, S1);

    k_gemm<<<dim3(256 * 2), 256, 0, stream>>>(T1, Wb2, b2, T2, pS, pQ, K12, 256);
    k_affine<<<dim3(1), 256, 0, stream>>>(pS, pQ, g2, be2, A2, S2, 256);

    k_final<<<dim3(N_ / 64, 4, B_), 256, 0, stream>>>(T2, A2, S2, (float*)d_out);
}

// Round 12
// 192.756 us; speedup vs baseline: 1.2771x; 1.2771x over previous
//
#include <hip/hip_runtime.h>

#define B_   8
#define N_   4096
#define S_   1024
#define M_   2048
#define D1_  128
#define D2_  256
#define CIN_ 388
#define KP0  416          // K of layer0, padded to 13*32
#define K12  512          // K of layers 1,2
#define J_   (B_ * N_)    // 32768
#define NE   16           // candidate splits
#define SS   (S_ / NE)    // 64 candidates per chunk
#define MM   (M_ / NE)    // 128 keypoints per chunk
#define NJB  256          // j-blocks per GEMM (J/128)
#define BN_EPS 1e-5f

typedef __bf16 bf16x8 __attribute__((ext_vector_type(8)));
typedef float  f32x4  __attribute__((ext_vector_type(4)));
typedef unsigned short ushort_t;

__device__ __forceinline__ float mulrn(float a, float b) { return __fmul_rn(a, b); }
__device__ __forceinline__ float addrn(float a, float b) { return __fadd_rn(a, b); }
__device__ __forceinline__ float subrn(float a, float b) { return __fsub_rn(a, b); }
__device__ __forceinline__ float norm3(float x, float y, float z) {
    return addrn(addrn(mulrn(x, x), mulrn(y, y)), mulrn(z, z));
}
__device__ __forceinline__ ushort_t f2bf(float f) {  // RNE
    unsigned int u = __float_as_uint(f);
    return (ushort_t)((u + 0x7FFFu + ((u >> 16) & 1u)) >> 16);
}
__device__ __forceinline__ float bf2f(ushort_t u) {
    return __uint_as_float(((unsigned int)u) << 16);
}
// lexicographic (d, idx) compare — reproduces stable top-k tie-breaking
__device__ __forceinline__ bool plt(float da, int ia, float db, int ib) {
    return (da < db) || (da == db && ia < ib);
}

// ---------------------------------------------------------------------------
// points2 [B][D2][S] -> p2t [B][S][D2]  (fp32, feeds exact interp math)
__global__ __launch_bounds__(256) void k_transpose_p2(const float* __restrict__ p2,
                                                      float* __restrict__ p2t) {
    __shared__ float tile[32][33];
    int b = blockIdx.z;
    int s0 = blockIdx.x * 32, c0 = blockIdx.y * 32;
    int tx = threadIdx.x, ty = threadIdx.y;  // 32 x 8
#pragma unroll
    for (int i = 0; i < 4; i++)
        tile[ty + i * 8][tx] = p2[(size_t)b * D2_ * S_ + (size_t)(c0 + ty + i * 8) * S_ + s0 + tx];
    __syncthreads();
#pragma unroll
    for (int i = 0; i < 4; i++)
        p2t[(size_t)b * S_ * D2_ + (size_t)(s0 + ty + i * 8) * D2_ + c0 + tx] = tile[tx][ty + i * 8];
}

// ---------------------------------------------------------------------------
// W [O][C] fp32 -> Wb [O][Kp] bf16, zero-padded cols (already k-contiguous)
__global__ __launch_bounds__(256) void k_prep_w(const float* __restrict__ W,
                                                ushort_t* __restrict__ Wb, int O, int C, int Kp) {
    int i = blockIdx.x * 256 + threadIdx.x;
    if (i >= O * Kp) return;
    int o = i / Kp, k = i - o * Kp;
    Wb[i] = (k < C) ? f2bf(W[(size_t)o * C + k]) : (ushort_t)0;
}

// ---------------------------------------------------------------------------
// points1 [B][D1][N] fp32 -> XT[j][0:128] bf16 (LDS tile transpose)
__global__ __launch_bounds__(256) void k_p1t(const float* __restrict__ p1,
                                             ushort_t* __restrict__ XT) {
    __shared__ ushort_t tile[32][132];
    int b = blockIdx.y;
    int n0 = blockIdx.x * 32;
    int t = threadIdx.x;

    {
        int nl = t & 31, cq = t >> 5;
#pragma unroll
        for (int k = 0; k < 16; k++) {
            int c = cq * 16 + k;
            tile[nl][c] = f2bf(p1[(size_t)b * D1_ * N_ + (size_t)c * N_ + n0 + nl]);
        }
    }
    __syncthreads();
    {
        int nl = t >> 3, sub = t & 7;
        size_t j = (size_t)b * N_ + n0 + nl;
#pragma unroll
        for (int k = 0; k < 4; k++) {
            int chunk = k * 8 + sub;
            *(uint2*)&XT[j * KP0 + chunk * 4] = *(const uint2*)&tile[nl][chunk * 4];
        }
    }
}

// ---------------------------------------------------------------------------
// Scan phase: one THREAD per query, one candidate-SIXTEENTH per block.
// 1024 blocks -> 4 blocks/CU (vs 2 at 8 splits): latency hiding doubles.
__global__ __launch_bounds__(512) void k_scan(const float* __restrict__ xyz1,
                                              const float* __restrict__ xyz2,
                                              const float* __restrict__ feature,
                                              float* __restrict__ outp) {
    __shared__ float4 sL[SS];
    __shared__ float4 fL[MM];
    int tid = threadIdx.x;
    int e = blockIdx.y;
    int j = blockIdx.x * 512 + tid;
    int b = blockIdx.x >> 3;           // 8 blocks.x per batch (4096/512)
    int n = j & (N_ - 1);

    for (int i = tid; i < SS + MM; i += 512) {
        if (i < SS) {
            int s = e * SS + i;
            float x = xyz2[(size_t)b * 3 * S_ + s];
            float y = xyz2[(size_t)b * 3 * S_ + S_ + s];
            float z = xyz2[(size_t)b * 3 * S_ + 2 * S_ + s];
            sL[i] = make_float4(x, y, z, norm3(x, y, z));
        } else {
            int m = e * MM + (i - SS);
            float4 f = *(const float4*)(feature + (size_t)b * M_ * 4 + (size_t)m * 4);
            fL[i - SS] = make_float4(f.y, f.z, f.w, norm3(f.y, f.z, f.w));
        }
    }
    __syncthreads();

    float qx = xyz1[(size_t)b * 3 * N_ + n];
    float qy = xyz1[(size_t)b * 3 * N_ + N_ + n];
    float qz = xyz1[(size_t)b * 3 * N_ + 2 * N_ + n];
    float qn = norm3(qx, qy, qz);

    float d0 = 1e30f, d1 = 1e30f, d2 = 1e30f;
    int i0 = 0, i1 = 0, i2 = 0;
#pragma unroll 4
    for (int i = 0; i < SS; i++) {
        float4 c = sL[i];
        float dot = addrn(addrn(mulrn(qx, c.x), mulrn(qy, c.y)), mulrn(qz, c.z));
        float d = subrn(addrn(qn, c.w), mulrn(2.0f, dot));
        int s = e * SS + i;
        bool l0 = d < d0, l1 = d < d1, l2 = d < d2;
        d2 = l1 ? d1 : (l2 ? d : d2);  i2 = l1 ? i1 : (l2 ? s : i2);
        d1 = l0 ? d0 : (l1 ? d : d1);  i1 = l0 ? i0 : (l1 ? s : i1);
        d0 = l0 ? d  : d0;             i0 = l0 ? s  : i0;
    }

    float dm = 1e30f; int im = 0;
#pragma unroll 4
    for (int i = 0; i < MM; i++) {
        float4 c = fL[i];
        float dot = addrn(addrn(mulrn(qx, c.x), mulrn(qy, c.y)), mulrn(qz, c.z));
        float d = subrn(addrn(qn, c.w), mulrn(2.0f, dot));
        if (d < dm) { dm = d; im = e * MM + i; }
    }

    float* o = outp + ((size_t)j * NE + e) * 8;
    float4 v0 = {d0, d1, d2, dm};
    float4 v1 = {__int_as_float(i0), __int_as_float(i1), __int_as_float(i2), __int_as_float(im)};
    *(float4*)o = v0;
    *(float4*)(o + 4) = v1;
}

// ---------------------------------------------------------------------------
// Merge + assembly: one WAVE per query; 4-step lexicographic butterfly merge
// over 16 partials (same verified network, one more step).
__global__ __launch_bounds__(256) void k_nn2(const float* __restrict__ feature,
                                             const float* __restrict__ p2t,
                                             const float* __restrict__ outp,
                                             ushort_t* __restrict__ XT) {
    int bq = blockIdx.y;
    int wid = threadIdx.x >> 6;
    int l = threadIdx.x & 63;
    int n = blockIdx.x * 4 + wid;
    size_t j = (size_t)bq * N_ + n;
    const float* fb = feature + (size_t)bq * M_ * 4;

    float d0 = 1e30f, d1 = 1e30f, d2 = 1e30f, dm = 1e30f;
    int i0 = 0, i1 = 0, i2 = 0, im = 0;
    if (l < NE) {
        const float* o = outp + (j * NE + l) * 8;
        float4 a = *(const float4*)o;
        float4 bi = *(const float4*)(o + 4);
        d0 = a.x; d1 = a.y; d2 = a.z; dm = a.w;
        i0 = __float_as_int(bi.x); i1 = __float_as_int(bi.y);
        i2 = __float_as_int(bi.z); im = __float_as_int(bi.w);
    }

#pragma unroll
    for (int off = 1; off < NE; off <<= 1) {
        float e0 = __shfl_xor(d0, off), e1 = __shfl_xor(d1, off), e2 = __shfl_xor(d2, off);
        int   f0 = __shfl_xor(i0, off), f1 = __shfl_xor(i1, off), f2 = __shfl_xor(i2, off);
        bool c0 = plt(e0, f0, d0, i0);
        float m0d = c0 ? e0 : d0; int m0i = c0 ? f0 : i0;
        float x0d = c0 ? d0 : e0; int x0i = c0 ? i0 : f0;
        bool c1 = plt(e1, f1, d1, i1);
        float n1d = c1 ? e1 : d1; int n1i = c1 ? f1 : i1;
        float z1d = c1 ? d1 : e1; int z1i = c1 ? i1 : f1;
        bool c2 = plt(e2, f2, d2, i2);
        float w2d = c2 ? e2 : d2; int w2i = c2 ? f2 : i2;
        bool c3 = plt(n1d, n1i, x0d, x0i);
        float r1d = c3 ? n1d : x0d; int r1i = c3 ? n1i : x0i;
        float t2d = c3 ? x0d : n1d; int t2i = c3 ? x0i : n1i;
        bool c4 = plt(t2d, t2i, z1d, z1i);
        float u2d = c4 ? t2d : z1d; int u2i = c4 ? t2i : z1i;
        bool c5 = plt(w2d, w2i, u2d, u2i);
        float r2d = c5 ? w2d : u2d; int r2i = c5 ? w2i : u2i;
        d0 = m0d; i0 = m0i; d1 = r1d; i1 = r1i; d2 = r2d; i2 = r2i;

        float ed = __shfl_xor(dm, off); int ei = __shfl_xor(im, off);
        if (plt(ed, ei, dm, im)) { dm = ed; im = ei; }
    }

    d0 = __shfl(d0, 0); d1 = __shfl(d1, 0); d2 = __shfl(d2, 0);
    i0 = __shfl(i0, 0); i1 = __shfl(i1, 0); i2 = __shfl(i2, 0);
    im = __shfl(im, 0);

    float w0 = 1.0f / addrn(d0, 1e-8f);
    float w1 = 1.0f / addrn(d1, 1e-8f);
    float w2 = 1.0f / addrn(d2, 1e-8f);
    float wsum = addrn(addrn(w0, w1), w2);
    w0 = w0 / wsum; w1 = w1 / wsum; w2 = w2 / wsum;

    ushort_t* xr = XT + j * KP0;
    const float* r0 = p2t + (size_t)bq * S_ * D2_ + (size_t)i0 * D2_;
    const float* r1 = p2t + (size_t)bq * S_ * D2_ + (size_t)i1 * D2_;
    const float* r2 = p2t + (size_t)bq * S_ * D2_ + (size_t)i2 * D2_;
    {
        int c = l * 4;
        float4 a = *(const float4*)(r0 + c);
        float4 bb = *(const float4*)(r1 + c);
        float4 cc = *(const float4*)(r2 + c);
        ushort_t tmp[4];
        tmp[0] = f2bf(addrn(addrn(mulrn(a.x, w0), mulrn(bb.x, w1)), mulrn(cc.x, w2)));
        tmp[1] = f2bf(addrn(addrn(mulrn(a.y, w0), mulrn(bb.y, w1)), mulrn(cc.y, w2)));
        tmp[2] = f2bf(addrn(addrn(mulrn(a.z, w0), mulrn(bb.z, w1)), mulrn(cc.z, w2)));
        tmp[3] = f2bf(addrn(addrn(mulrn(a.w, w0), mulrn(bb.w, w1)), mulrn(cc.w, w2)));
        *(uint2*)&xr[D1_ + c] = *(uint2*)tmp;
    }
    if (l < 8) {
        uint2 v = {0u, 0u};
        if (l == 0) {
            float4 nf = *(const float4*)(fb + (size_t)im * 4);
            ushort_t tmp[4] = {f2bf(nf.x), f2bf(nf.y), f2bf(nf.z), f2bf(nf.w)};
            v = *(uint2*)tmp;
        }
        *(uint2*)&xr[384 + l * 4] = v;
    }
}

// ---------------------------------------------------------------------------
// bf16 MFMA GEMM: T[j][o] = X[j][:]·W[o][:] + bias[o]. BN stats -> per-block
// partial arrays (plain coalesced stores, no atomics). Triple-buffered LDS,
// prefetch distance 2, counted s_waitcnt vmcnt(4) + raw s_barrier.
// Coalesced C-write via LDS bounce tile [128][136]. XCD-aware 1-D swizzle.
__global__ __launch_bounds__(256) void k_gemm(const ushort_t* __restrict__ Xb,
                                              const ushort_t* __restrict__ Wb,
                                              const float* __restrict__ bias,
                                              ushort_t* __restrict__ T,
                                              float* __restrict__ psumS,
                                              float* __restrict__ psumQ,
                                              int Kt, int Nout) {
    // 3 buffers x 16 KB (sA 8KB | sB 8KB) = 49152 B; stats 2 KB after.
    __shared__ __align__(16) char smem[51200];
    ushort_t* cb = (ushort_t*)smem;                    // bounce: 34816 B (aliases bufs)
    float* redS = (float*)(smem + 49152);              // 1 KB
    float* redQ = (float*)(smem + 50176);              // 1 KB

    int tid = threadIdx.x;
    int l = tid & 63;
    int w = tid >> 6;
    int wr = w >> 1, wc = w & 1;

    // XCD-aware bijective swizzle (grid = 256 * nY blocks, 1-D)
    int bid = blockIdx.x;
    int jb = (bid & 7) + (((bid >> 3) & 31) << 3);   // 0..255
    int ob = bid >> 8;
    int j0 = jb * 128, o0 = ob * 128;

    f32x4 acc[4][4] = {};
    int nt = Kt >> 5;

    auto stage = [&](int buf, int kt) {
        int k0 = kt << 5;
        ushort_t* base = (ushort_t*)(smem + buf * 16384);
#pragma unroll
        for (int e = 0; e < 2; ++e) {
            int i = e * 256 + tid;
            int row = i >> 2;
            int g = (i & 3) ^ ((row >> 1) & 3);   // pre-swizzled source chunk
            const ushort_t* ga = Xb + (size_t)(j0 + row) * Kt + k0 + g * 8;
            __builtin_amdgcn_global_load_lds(
                (const __attribute__((address_space(1))) void*)ga,
                (__attribute__((address_space(3))) void*)&base[i * 8], 16, 0, 0);
            const ushort_t* gb = Wb + (size_t)(o0 + row) * Kt + k0 + g * 8;
            __builtin_amdgcn_global_load_lds(
                (const __attribute__((address_space(1))) void*)gb,
                (__attribute__((address_space(3))) void*)&base[4096 + i * 8], 16, 0, 0);
        }
    };

    // prologue: 2 tiles in flight, wait only the first (vmcnt(4))
    stage(0, 0);
    stage(1, 1);
    asm volatile("s_waitcnt vmcnt(4)" ::: "memory");
    __builtin_amdgcn_s_barrier();

    for (int t = 0; t < nt; ++t) {
        if (t + 2 < nt) stage((t + 2) % 3, t + 2);

        ushort_t* base = (ushort_t*)(smem + (t % 3) * 16384);
        bf16x8 av[4], bv[4];
#pragma unroll
        for (int mi = 0; mi < 4; ++mi) {
            int r = wr * 64 + mi * 16 + (l & 15);
            int sl = (l >> 4) ^ ((r >> 1) & 3);
            av[mi] = *(const bf16x8*)&base[r * 32 + sl * 8];
        }
#pragma unroll
        for (int ni = 0; ni < 4; ++ni) {
            int r = wc * 64 + ni * 16 + (l & 15);
            int sl = (l >> 4) ^ ((r >> 1) & 3);
            bv[ni] = *(const bf16x8*)&base[4096 + r * 32 + sl * 8];
        }
#pragma unroll
        for (int mi = 0; mi < 4; ++mi)
#pragma unroll
            for (int ni = 0; ni < 4; ++ni)
                acc[mi][ni] = __builtin_amdgcn_mfma_f32_16x16x32_bf16(av[mi], bv[ni],
                                                                      acc[mi][ni], 0, 0, 0);
        // end-of-iter: need stage(t+1) complete; stage(t+2)'s 4 loads may fly.
        if (t + 2 < nt)      asm volatile("s_waitcnt vmcnt(4)" ::: "memory");
        else if (t + 1 < nt) asm volatile("s_waitcnt vmcnt(0)" ::: "memory");
        __builtin_amdgcn_s_barrier();
    }

    // ---- epilogue: stats from regs + bounce acc -> LDS -> coalesced stores
    float csum[4], csq[4];
#pragma unroll
    for (int ni = 0; ni < 4; ++ni) { csum[ni] = 0.f; csq[ni] = 0.f; }

#pragma unroll
    for (int ni = 0; ni < 4; ++ni) {
        int oc = wc * 64 + ni * 16 + (l & 15);
        float bi = bias[o0 + oc];
#pragma unroll
        for (int mi = 0; mi < 4; ++mi) {
            int jr = wr * 64 + mi * 16 + (l >> 4) * 4;
#pragma unroll
            for (int r = 0; r < 4; ++r) {
                float v = acc[mi][ni][r] + bi;
                csum[ni] += v;
                csq[ni] += v * v;
                cb[(jr + r) * 136 + oc] = f2bf(v);
            }
        }
    }

#pragma unroll
    for (int ni = 0; ni < 4; ++ni) {
        float s = csum[ni], q = csq[ni];
        s += __shfl_xor(s, 16); s += __shfl_xor(s, 32);
        q += __shfl_xor(q, 16); q += __shfl_xor(q, 32);
        if ((l & 48) == 0) {
            int oc = wc * 64 + ni * 16 + (l & 15);
            redS[oc * 2 + wr] = s;
            redQ[oc * 2 + wr] = q;
        }
    }
    __syncthreads();

    if (tid < 128) {
        psumS[(size_t)jb * Nout + o0 + tid] = redS[tid * 2] + redS[tid * 2 + 1];
        psumQ[(size_t)jb * Nout + o0 + tid] = redQ[tid * 2] + redQ[tid * 2 + 1];
    }
#pragma unroll
    for (int p = 0; p < 8; ++p) {
        int idx = p * 256 + tid;
        int jr = idx >> 4, oc8 = (idx & 15) * 8;
        uint4 v = *(const uint4*)&cb[jr * 136 + oc8];
        *(uint4*)&T[(size_t)(j0 + jr) * Nout + o0 + oc8] = v;
    }
}

// ---------------------------------------------------------------------------
// Hierarchical reduce of per-block partials -> BN affine (a, s): y = a*x + s.
// Block: 16 channels x 16 partial-chunks; each thread sums 16 rows (coalesced);
// LDS tree over the 16 chunks. Grid = C/16 blocks.
__global__ __launch_bounds__(256) void k_affine(const float* __restrict__ pS,
                                                const float* __restrict__ pQ,
                                                const float* __restrict__ g,
                                                const float* __restrict__ be,
                                                float* __restrict__ A,
                                                float* __restrict__ S, int C) {
    __shared__ float rs[16][17], rq[16][17];
    int t = threadIdx.x;
    int ch = t & 15, part = t >> 4;      // 16 x 16
    int o = blockIdx.x * 16 + ch;
    float s = 0.f, q = 0.f;
#pragma unroll
    for (int k = 0; k < 16; k++) {
        int jb = part * 16 + k;
        s += pS[(size_t)jb * C + o];
        q += pQ[(size_t)jb * C + o];
    }
    rs[part][ch] = s; rq[part][ch] = q;
    __syncthreads();
    if (t < 16) {
        float ss = 0.f, qq = 0.f;
        for (int p = 0; p < 16; p++) { ss += rs[p][t]; qq += rq[p][t]; }
        int oo = blockIdx.x * 16 + t;
        float mean = ss / (float)J_;
        float var = qq / (float)J_ - mean * mean;
        float a = g[oo] * rsqrtf(var + BN_EPS);
        A[oo] = a;
        S[oo] = be[oo] - a * mean;
    }
}

// ---------------------------------------------------------------------------
// In-place BN+ReLU on T [J][512] bf16 (channel = col = idx & 511)
__global__ __launch_bounds__(256) void k_norm(ushort_t* __restrict__ T,
                                              const float* __restrict__ A,
                                              const float* __restrict__ S) {
    size_t idx = ((size_t)blockIdx.x * 256 + threadIdx.x) * 8;
    int o = (int)(idx & 511);
    uint4 v = *(uint4*)&T[idx];
    ushort_t* pu = (ushort_t*)&v;
#pragma unroll
    for (int i = 0; i < 8; i++) {
        float f = bf2f(pu[i]);
        f = fmaxf(A[o + i] * f + S[o + i], 0.f);
        pu[i] = f2bf(f);
    }
    *(uint4*)&T[idx] = v;
}

// ---------------------------------------------------------------------------
// T2 [J][256] bf16 + BN affine + ReLU -> out [B][256][N] fp32 (transpose)
__global__ __launch_bounds__(256) void k_final(const ushort_t* __restrict__ T2,
                                               const float* __restrict__ A,
                                               const float* __restrict__ S,
                                               float* __restrict__ out) {
    __shared__ float tile[64][65];
    int tid = threadIdx.x;
    int jb = blockIdx.z * N_ + blockIdx.x * 64;
    int o0 = blockIdx.y * 64;

    int r = tid >> 2, cq = (tid & 3) * 16;
    uint4 v = *(const uint4*)&T2[(size_t)(jb + r) * 256 + o0 + cq];
    ushort_t* pu = (ushort_t*)&v;
#pragma unroll
    for (int i = 0; i < 8; i++) {
        int o = o0 + cq + i;
        tile[r][cq + i] = fmaxf(A[o] * bf2f(pu[i]) + S[o], 0.f);
    }
    uint4 v2 = *(const uint4*)&T2[(size_t)(jb + r) * 256 + o0 + cq + 8];
    pu = (ushort_t*)&v2;
#pragma unroll
    for (int i = 0; i < 8; i++) {
        int o = o0 + cq + 8 + i;
        tile[r][cq + 8 + i] = fmaxf(A[o] * bf2f(pu[i]) + S[o], 0.f);
    }
    __syncthreads();

    int ro = tid >> 2, jq = (tid & 3) * 16;
    float* orow = out + ((size_t)blockIdx.z * 256 + o0 + ro) * N_ + blockIdx.x * 64 + jq;
#pragma unroll
    for (int h = 0; h < 4; h++) {
        float4 ov = {tile[jq + h * 4 + 0][ro], tile[jq + h * 4 + 1][ro],
                     tile[jq + h * 4 + 2][ro], tile[jq + h * 4 + 3][ro]};
        *(float4*)(orow + h * 4) = ov;
    }
}

// ---------------------------------------------------------------------------
extern "C" void kernel_launch(void* const* d_in, const int* in_sizes, int n_in,
                              void* d_out, int out_size, void* d_ws, size_t ws_size,
                              hipStream_t stream) {
    (void)in_sizes; (void)n_in; (void)out_size; (void)ws_size;
    const float* xyz1    = (const float*)d_in[0];
    const float* xyz2    = (const float*)d_in[1];
    const float* points1 = (const float*)d_in[2];
    const float* points2 = (const float*)d_in[3];
    const float* feature = (const float*)d_in[4];
    const float* W0 = (const float*)d_in[5];
    const float* b0 = (const float*)d_in[6];
    const float* g0 = (const float*)d_in[7];
    const float* be0 = (const float*)d_in[8];
    const float* W1 = (const float*)d_in[9];
    const float* b1 = (const float*)d_in[10];
    const float* g1 = (const float*)d_in[11];
    const float* be1 = (const float*)d_in[12];
    const float* W2 = (const float*)d_in[13];
    const float* b2 = (const float*)d_in[14];
    const float* g2 = (const float*)d_in[15];
    const float* be2 = (const float*)d_in[16];

    char* ws = (char*)d_ws;
    size_t off = 0;
    auto carve = [&](size_t bytes) { char* p = ws + off; off += (bytes + 255) & ~(size_t)255; return p; };

    ushort_t* XT  = (ushort_t*)carve((size_t)J_ * KP0 * 2);
    ushort_t* T0  = (ushort_t*)carve((size_t)J_ * 512 * 2);
    ushort_t* T1  = (ushort_t*)carve((size_t)J_ * 512 * 2);
    ushort_t* T2  = (ushort_t*)carve((size_t)J_ * 256 * 2);
    float*    p2t = (float*)carve((size_t)B_ * S_ * D2_ * 4);
    float*    nnp = (float*)carve((size_t)J_ * NE * 8 * 4);
    ushort_t* Wb0 = (ushort_t*)carve((size_t)512 * KP0 * 2);
    ushort_t* Wb1 = (ushort_t*)carve((size_t)512 * K12 * 2);
    ushort_t* Wb2 = (ushort_t*)carve((size_t)256 * K12 * 2);
    float*    pS  = (float*)carve((size_t)NJB * 512 * 4);   // per-block partial sums
    float*    pQ  = (float*)carve((size_t)NJB * 512 * 4);   // per-block partial sumsq
    float*    af  = (float*)carve(2560 * 4);
    float *A0 = af, *S0 = af + 512, *A1 = af + 1024, *S1 = af + 1536, *A2 = af + 2048, *S2 = af + 2304;

    k_prep_w<<<dim3((512 * KP0 + 255) / 256), 256, 0, stream>>>(W0, Wb0, 512, CIN_, KP0);
    k_prep_w<<<dim3((512 * K12 + 255) / 256), 256, 0, stream>>>(W1, Wb1, 512, 512, K12);
    k_prep_w<<<dim3((512 * 256 + 255) / 256), 256, 0, stream>>>(W2, Wb2, 256, 512, K12);
    k_transpose_p2<<<dim3(S_ / 32, D2_ / 32, B_), dim3(32, 8), 0, stream>>>(points2, p2t);
    k_p1t<<<dim3(N_ / 32, B_), 256, 0, stream>>>(points1, XT);
    k_scan<<<dim3(J_ / 512, NE), 512, 0, stream>>>(xyz1, xyz2, feature, nnp);
    k_nn2<<<dim3(N_ / 4, B_), 256, 0, stream>>>(feature, p2t, nnp, XT);

    k_gemm<<<dim3(256 * 4), 256, 0, stream>>>(XT, Wb0, b0, T0, pS, pQ, KP0, 512);
    k_affine<<<dim3(512 / 16), 256, 0, stream>>>(pS, pQ, g0, be0, A0, S0, 512);
    k_norm<<<dim3((int)((size_t)J_ * 512 / 8 / 256)), 256, 0, stream>>>(T0, A0, S0);

    k_gemm<<<dim3(256 * 4), 256, 0, stream>>>(T0, Wb1, b1, T1, pS, pQ, K12, 512);
    k_affine<<<dim3(512 / 16), 256, 0, stream>>>(pS, pQ, g1, be1, A1, S1, 512);
    k_norm<<<dim3((int)((size_t)J_ * 512 / 8 / 256)), 256, 0, stream>>>(T1, A1, S1);

    k_gemm<<<dim3(256 * 2), 256, 0, stream>>>(T1, Wb2, b2, T2, pS, pQ, K12, 256);
    k_affine<<<dim3(256 / 16), 256, 0, stream>>>(pS, pQ, g2, be2, A2, S2, 256);

    k_final<<<dim3(N_ / 64, 4, B_), 256, 0, stream>>>(T2, A2, S2, (float*)d_out);
}

// Round 13
// 192.107 us; speedup vs baseline: 1.2814x; 1.0034x over previous
//
#include <hip/hip_runtime.h>

#define B_   8
#define N_   4096
#define S_   1024
#define M_   2048
#define D1_  128
#define D2_  256
#define CIN_ 388
#define KP0  416          // K of layer0, padded to 13*32
#define K12  512          // K of layers 1,2
#define J_   (B_ * N_)    // 32768
#define NE   16           // candidate splits
#define SS   (S_ / NE)    // 64 candidates per chunk
#define MM   (M_ / NE)    // 128 keypoints per chunk
#define NJB  256          // j-blocks per GEMM (J/128)
#define BN_EPS 1e-5f

typedef __bf16 bf16x8 __attribute__((ext_vector_type(8)));
typedef float  f32x4  __attribute__((ext_vector_type(4)));
typedef unsigned short ushort_t;

__device__ __forceinline__ float mulrn(float a, float b) { return __fmul_rn(a, b); }
__device__ __forceinline__ float addrn(float a, float b) { return __fadd_rn(a, b); }
__device__ __forceinline__ float subrn(float a, float b) { return __fsub_rn(a, b); }
__device__ __forceinline__ float norm3(float x, float y, float z) {
    return addrn(addrn(mulrn(x, x), mulrn(y, y)), mulrn(z, z));
}
__device__ __forceinline__ ushort_t f2bf(float f) {  // RNE
    unsigned int u = __float_as_uint(f);
    return (ushort_t)((u + 0x7FFFu + ((u >> 16) & 1u)) >> 16);
}
__device__ __forceinline__ float bf2f(ushort_t u) {
    return __uint_as_float(((unsigned int)u) << 16);
}
// lexicographic (d, idx) compare — reproduces stable top-k tie-breaking
__device__ __forceinline__ bool plt(float da, int ia, float db, int ib) {
    return (da < db) || (da == db && ia < ib);
}

// ---------------------------------------------------------------------------
// points2 [B][D2][S] -> p2t [B][S][D2]  (fp32, feeds exact interp math)
__global__ __launch_bounds__(256) void k_transpose_p2(const float* __restrict__ p2,
                                                      float* __restrict__ p2t) {
    __shared__ float tile[32][33];
    int b = blockIdx.z;
    int s0 = blockIdx.x * 32, c0 = blockIdx.y * 32;
    int tx = threadIdx.x, ty = threadIdx.y;  // 32 x 8
#pragma unroll
    for (int i = 0; i < 4; i++)
        tile[ty + i * 8][tx] = p2[(size_t)b * D2_ * S_ + (size_t)(c0 + ty + i * 8) * S_ + s0 + tx];
    __syncthreads();
#pragma unroll
    for (int i = 0; i < 4; i++)
        p2t[(size_t)b * S_ * D2_ + (size_t)(s0 + ty + i * 8) * D2_ + c0 + tx] = tile[tx][ty + i * 8];
}

// ---------------------------------------------------------------------------
// W [O][C] fp32 -> Wb [O][Kp] bf16, zero-padded cols (already k-contiguous)
__global__ __launch_bounds__(256) void k_prep_w(const float* __restrict__ W,
                                                ushort_t* __restrict__ Wb, int O, int C, int Kp) {
    int i = blockIdx.x * 256 + threadIdx.x;
    if (i >= O * Kp) return;
    int o = i / Kp, k = i - o * Kp;
    Wb[i] = (k < C) ? f2bf(W[(size_t)o * C + k]) : (ushort_t)0;
}

// ---------------------------------------------------------------------------
// points1 [B][D1][N] fp32 -> XT[j][0:128] bf16 (LDS tile transpose)
__global__ __launch_bounds__(256) void k_p1t(const float* __restrict__ p1,
                                             ushort_t* __restrict__ XT) {
    __shared__ ushort_t tile[32][132];
    int b = blockIdx.y;
    int n0 = blockIdx.x * 32;
    int t = threadIdx.x;

    {
        int nl = t & 31, cq = t >> 5;
#pragma unroll
        for (int k = 0; k < 16; k++) {
            int c = cq * 16 + k;
            tile[nl][c] = f2bf(p1[(size_t)b * D1_ * N_ + (size_t)c * N_ + n0 + nl]);
        }
    }
    __syncthreads();
    {
        int nl = t >> 3, sub = t & 7;
        size_t j = (size_t)b * N_ + n0 + nl;
#pragma unroll
        for (int k = 0; k < 4; k++) {
            int chunk = k * 8 + sub;
            *(uint2*)&XT[j * KP0 + chunk * 4] = *(const uint2*)&tile[nl][chunk * 4];
        }
    }
}

// ---------------------------------------------------------------------------
// Scan phase: TWO queries per thread (shared candidate reads, 2 independent
// dep chains), one candidate-SIXTEENTH per block. 256 threads x 512 queries.
// Distance arithmetic bit-identical to prior rounds (unfused expansion).
// Value updates use branch-free min/med form (case-equivalent given the
// d0<=d1<=d2 sortedness invariant); index updates keep strict-< semantics.
__global__ __launch_bounds__(256) void k_scan(const float* __restrict__ xyz1,
                                              const float* __restrict__ xyz2,
                                              const float* __restrict__ feature,
                                              float* __restrict__ outp) {
    __shared__ float4 sL[SS];
    __shared__ float4 fL[MM];
    int tid = threadIdx.x;
    int e = blockIdx.y;
    int b = blockIdx.x >> 3;           // 8 blocks.x per batch (4096/512)
    int jA = blockIdx.x * 512 + tid;   // query A
    int jB = jA + 256;                 // query B
    int nA = jA & (N_ - 1);
    int nB = nA + 256;

    for (int i = tid; i < SS + MM; i += 256) {
        if (i < SS) {
            int s = e * SS + i;
            float x = xyz2[(size_t)b * 3 * S_ + s];
            float y = xyz2[(size_t)b * 3 * S_ + S_ + s];
            float z = xyz2[(size_t)b * 3 * S_ + 2 * S_ + s];
            sL[i] = make_float4(x, y, z, norm3(x, y, z));
        } else {
            int m = e * MM + (i - SS);
            float4 f = *(const float4*)(feature + (size_t)b * M_ * 4 + (size_t)m * 4);
            fL[i - SS] = make_float4(f.y, f.z, f.w, norm3(f.y, f.z, f.w));
        }
    }
    __syncthreads();

    const float* xb = xyz1 + (size_t)b * 3 * N_;
    float qxA = xb[nA], qyA = xb[N_ + nA], qzA = xb[2 * N_ + nA];
    float qxB = xb[nB], qyB = xb[N_ + nB], qzB = xb[2 * N_ + nB];
    float qnA = norm3(qxA, qyA, qzA);
    float qnB = norm3(qxB, qyB, qzB);

    float d0A = 1e30f, d1A = 1e30f, d2A = 1e30f;
    float d0B = 1e30f, d1B = 1e30f, d2B = 1e30f;
    int i0A = 0, i1A = 0, i2A = 0, i0B = 0, i1B = 0, i2B = 0;
#pragma unroll 4
    for (int i = 0; i < SS; i++) {
        float4 c = sL[i];
        int s = e * SS + i;
        float dotA = addrn(addrn(mulrn(qxA, c.x), mulrn(qyA, c.y)), mulrn(qzA, c.z));
        float dA = subrn(addrn(qnA, c.w), mulrn(2.0f, dotA));
        float dotB = addrn(addrn(mulrn(qxB, c.x), mulrn(qyB, c.y)), mulrn(qzB, c.z));
        float dB = subrn(addrn(qnB, c.w), mulrn(2.0f, dotB));
        {
            bool l0 = dA < d0A, l1 = dA < d1A, l2 = dA < d2A;
            i2A = l1 ? i1A : (l2 ? s : i2A);
            i1A = l0 ? i0A : (l1 ? s : i1A);
            i0A = l0 ? s : i0A;
            d2A = fminf(fmaxf(dA, d1A), d2A);
            d1A = fminf(fmaxf(dA, d0A), d1A);
            d0A = fminf(dA, d0A);
        }
        {
            bool l0 = dB < d0B, l1 = dB < d1B, l2 = dB < d2B;
            i2B = l1 ? i1B : (l2 ? s : i2B);
            i1B = l0 ? i0B : (l1 ? s : i1B);
            i0B = l0 ? s : i0B;
            d2B = fminf(fmaxf(dB, d1B), d2B);
            d1B = fminf(fmaxf(dB, d0B), d1B);
            d0B = fminf(dB, d0B);
        }
    }

    float dmA = 1e30f, dmB = 1e30f;
    int imA = 0, imB = 0;
#pragma unroll 4
    for (int i = 0; i < MM; i++) {
        float4 c = fL[i];
        int m = e * MM + i;
        float dotA = addrn(addrn(mulrn(qxA, c.x), mulrn(qyA, c.y)), mulrn(qzA, c.z));
        float dA = subrn(addrn(qnA, c.w), mulrn(2.0f, dotA));
        float dotB = addrn(addrn(mulrn(qxB, c.x), mulrn(qyB, c.y)), mulrn(qzB, c.z));
        float dB = subrn(addrn(qnB, c.w), mulrn(2.0f, dotB));
        imA = (dA < dmA) ? m : imA;
        dmA = fminf(dA, dmA);
        imB = (dB < dmB) ? m : imB;
        dmB = fminf(dB, dmB);
    }

    {
        float* o = outp + ((size_t)jA * NE + e) * 8;
        float4 v0 = {d0A, d1A, d2A, dmA};
        float4 v1 = {__int_as_float(i0A), __int_as_float(i1A), __int_as_float(i2A), __int_as_float(imA)};
        *(float4*)o = v0;
        *(float4*)(o + 4) = v1;
    }
    {
        float* o = outp + ((size_t)jB * NE + e) * 8;
        float4 v0 = {d0B, d1B, d2B, dmB};
        float4 v1 = {__int_as_float(i0B), __int_as_float(i1B), __int_as_float(i2B), __int_as_float(imB)};
        *(float4*)o = v0;
        *(float4*)(o + 4) = v1;
    }
}

// ---------------------------------------------------------------------------
// Merge + assembly: one WAVE per query; 4-step lexicographic butterfly merge
// over 16 partials (same verified network).
__global__ __launch_bounds__(256) void k_nn2(const float* __restrict__ feature,
                                             const float* __restrict__ p2t,
                                             const float* __restrict__ outp,
                                             ushort_t* __restrict__ XT) {
    int bq = blockIdx.y;
    int wid = threadIdx.x >> 6;
    int l = threadIdx.x & 63;
    int n = blockIdx.x * 4 + wid;
    size_t j = (size_t)bq * N_ + n;
    const float* fb = feature + (size_t)bq * M_ * 4;

    float d0 = 1e30f, d1 = 1e30f, d2 = 1e30f, dm = 1e30f;
    int i0 = 0, i1 = 0, i2 = 0, im = 0;
    if (l < NE) {
        const float* o = outp + (j * NE + l) * 8;
        float4 a = *(const float4*)o;
        float4 bi = *(const float4*)(o + 4);
        d0 = a.x; d1 = a.y; d2 = a.z; dm = a.w;
        i0 = __float_as_int(bi.x); i1 = __float_as_int(bi.y);
        i2 = __float_as_int(bi.z); im = __float_as_int(bi.w);
    }

#pragma unroll
    for (int off = 1; off < NE; off <<= 1) {
        float e0 = __shfl_xor(d0, off), e1 = __shfl_xor(d1, off), e2 = __shfl_xor(d2, off);
        int   f0 = __shfl_xor(i0, off), f1 = __shfl_xor(i1, off), f2 = __shfl_xor(i2, off);
        bool c0 = plt(e0, f0, d0, i0);
        float m0d = c0 ? e0 : d0; int m0i = c0 ? f0 : i0;
        float x0d = c0 ? d0 : e0; int x0i = c0 ? i0 : f0;
        bool c1 = plt(e1, f1, d1, i1);
        float n1d = c1 ? e1 : d1; int n1i = c1 ? f1 : i1;
        float z1d = c1 ? d1 : e1; int z1i = c1 ? i1 : f1;
        bool c2 = plt(e2, f2, d2, i2);
        float w2d = c2 ? e2 : d2; int w2i = c2 ? f2 : i2;
        bool c3 = plt(n1d, n1i, x0d, x0i);
        float r1d = c3 ? n1d : x0d; int r1i = c3 ? n1i : x0i;
        float t2d = c3 ? x0d : n1d; int t2i = c3 ? x0i : n1i;
        bool c4 = plt(t2d, t2i, z1d, z1i);
        float u2d = c4 ? t2d : z1d; int u2i = c4 ? t2i : z1i;
        bool c5 = plt(w2d, w2i, u2d, u2i);
        float r2d = c5 ? w2d : u2d; int r2i = c5 ? w2i : u2i;
        d0 = m0d; i0 = m0i; d1 = r1d; i1 = r1i; d2 = r2d; i2 = r2i;

        float ed = __shfl_xor(dm, off); int ei = __shfl_xor(im, off);
        if (plt(ed, ei, dm, im)) { dm = ed; im = ei; }
    }

    d0 = __shfl(d0, 0); d1 = __shfl(d1, 0); d2 = __shfl(d2, 0);
    i0 = __shfl(i0, 0); i1 = __shfl(i1, 0); i2 = __shfl(i2, 0);
    im = __shfl(im, 0);

    float w0 = 1.0f / addrn(d0, 1e-8f);
    float w1 = 1.0f / addrn(d1, 1e-8f);
    float w2 = 1.0f / addrn(d2, 1e-8f);
    float wsum = addrn(addrn(w0, w1), w2);
    w0 = w0 / wsum; w1 = w1 / wsum; w2 = w2 / wsum;

    ushort_t* xr = XT + j * KP0;
    const float* r0 = p2t + (size_t)bq * S_ * D2_ + (size_t)i0 * D2_;
    const float* r1 = p2t + (size_t)bq * S_ * D2_ + (size_t)i1 * D2_;
    const float* r2 = p2t + (size_t)bq * S_ * D2_ + (size_t)i2 * D2_;
    {
        int c = l * 4;
        float4 a = *(const float4*)(r0 + c);
        float4 bb = *(const float4*)(r1 + c);
        float4 cc = *(const float4*)(r2 + c);
        ushort_t tmp[4];
        tmp[0] = f2bf(addrn(addrn(mulrn(a.x, w0), mulrn(bb.x, w1)), mulrn(cc.x, w2)));
        tmp[1] = f2bf(addrn(addrn(mulrn(a.y, w0), mulrn(bb.y, w1)), mulrn(cc.y, w2)));
        tmp[2] = f2bf(addrn(addrn(mulrn(a.z, w0), mulrn(bb.z, w1)), mulrn(cc.z, w2)));
        tmp[3] = f2bf(addrn(addrn(mulrn(a.w, w0), mulrn(bb.w, w1)), mulrn(cc.w, w2)));
        *(uint2*)&xr[D1_ + c] = *(uint2*)tmp;
    }
    if (l < 8) {
        uint2 v = {0u, 0u};
        if (l == 0) {
            float4 nf = *(const float4*)(fb + (size_t)im * 4);
            ushort_t tmp[4] = {f2bf(nf.x), f2bf(nf.y), f2bf(nf.z), f2bf(nf.w)};
            v = *(uint2*)tmp;
        }
        *(uint2*)&xr[384 + l * 4] = v;
    }
}

// ---------------------------------------------------------------------------
// bf16 MFMA GEMM: T[j][o] = X[j][:]·W[o][:] + bias[o]. BN stats -> per-block
// partial arrays (plain coalesced stores, no atomics). Triple-buffered LDS,
// prefetch distance 2, counted s_waitcnt vmcnt(4) + raw s_barrier.
// Coalesced C-write via LDS bounce tile [128][136]. XCD-aware 1-D swizzle.
__global__ __launch_bounds__(256) void k_gemm(const ushort_t* __restrict__ Xb,
                                              const ushort_t* __restrict__ Wb,
                                              const float* __restrict__ bias,
                                              ushort_t* __restrict__ T,
                                              float* __restrict__ psumS,
                                              float* __restrict__ psumQ,
                                              int Kt, int Nout) {
    // 3 buffers x 16 KB (sA 8KB | sB 8KB) = 49152 B; stats 2 KB after.
    __shared__ __align__(16) char smem[51200];
    ushort_t* cb = (ushort_t*)smem;                    // bounce: 34816 B (aliases bufs)
    float* redS = (float*)(smem + 49152);              // 1 KB
    float* redQ = (float*)(smem + 50176);              // 1 KB

    int tid = threadIdx.x;
    int l = tid & 63;
    int w = tid >> 6;
    int wr = w >> 1, wc = w & 1;

    // XCD-aware bijective swizzle (grid = 256 * nY blocks, 1-D)
    int bid = blockIdx.x;
    int jb = (bid & 7) + (((bid >> 3) & 31) << 3);   // 0..255
    int ob = bid >> 8;
    int j0 = jb * 128, o0 = ob * 128;

    f32x4 acc[4][4] = {};
    int nt = Kt >> 5;

    auto stage = [&](int buf, int kt) {
        int k0 = kt << 5;
        ushort_t* base = (ushort_t*)(smem + buf * 16384);
#pragma unroll
        for (int e = 0; e < 2; ++e) {
            int i = e * 256 + tid;
            int row = i >> 2;
            int g = (i & 3) ^ ((row >> 1) & 3);   // pre-swizzled source chunk
            const ushort_t* ga = Xb + (size_t)(j0 + row) * Kt + k0 + g * 8;
            __builtin_amdgcn_global_load_lds(
                (const __attribute__((address_space(1))) void*)ga,
                (__attribute__((address_space(3))) void*)&base[i * 8], 16, 0, 0);
            const ushort_t* gb = Wb + (size_t)(o0 + row) * Kt + k0 + g * 8;
            __builtin_amdgcn_global_load_lds(
                (const __attribute__((address_space(1))) void*)gb,
                (__attribute__((address_space(3))) void*)&base[4096 + i * 8], 16, 0, 0);
        }
    };

    // prologue: 2 tiles in flight, wait only the first (vmcnt(4))
    stage(0, 0);
    stage(1, 1);
    asm volatile("s_waitcnt vmcnt(4)" ::: "memory");
    __builtin_amdgcn_s_barrier();

    for (int t = 0; t < nt; ++t) {
        if (t + 2 < nt) stage((t + 2) % 3, t + 2);

        ushort_t* base = (ushort_t*)(smem + (t % 3) * 16384);
        bf16x8 av[4], bv[4];
#pragma unroll
        for (int mi = 0; mi < 4; ++mi) {
            int r = wr * 64 + mi * 16 + (l & 15);
            int sl = (l >> 4) ^ ((r >> 1) & 3);
            av[mi] = *(const bf16x8*)&base[r * 32 + sl * 8];
        }
#pragma unroll
        for (int ni = 0; ni < 4; ++ni) {
            int r = wc * 64 + ni * 16 + (l & 15);
            int sl = (l >> 4) ^ ((r >> 1) & 3);
            bv[ni] = *(const bf16x8*)&base[4096 + r * 32 + sl * 8];
        }
#pragma unroll
        for (int mi = 0; mi < 4; ++mi)
#pragma unroll
            for (int ni = 0; ni < 4; ++ni)
                acc[mi][ni] = __builtin_amdgcn_mfma_f32_16x16x32_bf16(av[mi], bv[ni],
                                                                      acc[mi][ni], 0, 0, 0);
        // end-of-iter: need stage(t+1) complete; stage(t+2)'s 4 loads may fly.
        if (t + 2 < nt)      asm volatile("s_waitcnt vmcnt(4)" ::: "memory");
        else if (t + 1 < nt) asm volatile("s_waitcnt vmcnt(0)" ::: "memory");
        __builtin_amdgcn_s_barrier();
    }

    // ---- epilogue: stats from regs + bounce acc -> LDS -> coalesced stores
    float csum[4], csq[4];
#pragma unroll
    for (int ni = 0; ni < 4; ++ni) { csum[ni] = 0.f; csq[ni] = 0.f; }

#pragma unroll
    for (int ni = 0; ni < 4; ++ni) {
        int oc = wc * 64 + ni * 16 + (l & 15);
        float bi = bias[o0 + oc];
#pragma unroll
        for (int mi = 0; mi < 4; ++mi) {
            int jr = wr * 64 + mi * 16 + (l >> 4) * 4;
#pragma unroll
            for (int r = 0; r < 4; ++r) {
                float v = acc[mi][ni][r] + bi;
                csum[ni] += v;
                csq[ni] += v * v;
                cb[(jr + r) * 136 + oc] = f2bf(v);
            }
        }
    }

#pragma unroll
    for (int ni = 0; ni < 4; ++ni) {
        float s = csum[ni], q = csq[ni];
        s += __shfl_xor(s, 16); s += __shfl_xor(s, 32);
        q += __shfl_xor(q, 16); q += __shfl_xor(q, 32);
        if ((l & 48) == 0) {
            int oc = wc * 64 + ni * 16 + (l & 15);
            redS[oc * 2 + wr] = s;
            redQ[oc * 2 + wr] = q;
        }
    }
    __syncthreads();

    if (tid < 128) {
        psumS[(size_t)jb * Nout + o0 + tid] = redS[tid * 2] + redS[tid * 2 + 1];
        psumQ[(size_t)jb * Nout + o0 + tid] = redQ[tid * 2] + redQ[tid * 2 + 1];
    }
#pragma unroll
    for (int p = 0; p < 8; ++p) {
        int idx = p * 256 + tid;
        int jr = idx >> 4, oc8 = (idx & 15) * 8;
        uint4 v = *(const uint4*)&cb[jr * 136 + oc8];
        *(uint4*)&T[(size_t)(j0 + jr) * Nout + o0 + oc8] = v;
    }
}

// ---------------------------------------------------------------------------
// Hierarchical reduce of per-block partials -> BN affine (a, s): y = a*x + s.
__global__ __launch_bounds__(256) void k_affine(const float* __restrict__ pS,
                                                const float* __restrict__ pQ,
                                                const float* __restrict__ g,
                                                const float* __restrict__ be,
                                                float* __restrict__ A,
                                                float* __restrict__ S, int C) {
    __shared__ float rs[16][17], rq[16][17];
    int t = threadIdx.x;
    int ch = t & 15, part = t >> 4;      // 16 x 16
    int o = blockIdx.x * 16 + ch;
    float s = 0.f, q = 0.f;
#pragma unroll
    for (int k = 0; k < 16; k++) {
        int jb = part * 16 + k;
        s += pS[(size_t)jb * C + o];
        q += pQ[(size_t)jb * C + o];
    }
    rs[part][ch] = s; rq[part][ch] = q;
    __syncthreads();
    if (t < 16) {
        float ss = 0.f, qq = 0.f;
        for (int p = 0; p < 16; p++) { ss += rs[p][t]; qq += rq[p][t]; }
        int oo = blockIdx.x * 16 + t;
        float mean = ss / (float)J_;
        float var = qq / (float)J_ - mean * mean;
        float a = g[oo] * rsqrtf(var + BN_EPS);
        A[oo] = a;
        S[oo] = be[oo] - a * mean;
    }
}

// ---------------------------------------------------------------------------
// In-place BN+ReLU on T [J][512] bf16 (channel = col = idx & 511)
__global__ __launch_bounds__(256) void k_norm(ushort_t* __restrict__ T,
                                              const float* __restrict__ A,
                                              const float* __restrict__ S) {
    size_t idx = ((size_t)blockIdx.x * 256 + threadIdx.x) * 8;
    int o = (int)(idx & 511);
    uint4 v = *(uint4*)&T[idx];
    ushort_t* pu = (ushort_t*)&v;
#pragma unroll
    for (int i = 0; i < 8; i++) {
        float f = bf2f(pu[i]);
        f = fmaxf(A[o + i] * f + S[o + i], 0.f);
        pu[i] = f2bf(f);
    }
    *(uint4*)&T[idx] = v;
}

// ---------------------------------------------------------------------------
// T2 [J][256] bf16 + BN affine + ReLU -> out [B][256][N] fp32 (transpose)
__global__ __launch_bounds__(256) void k_final(const ushort_t* __restrict__ T2,
                                               const float* __restrict__ A,
                                               const float* __restrict__ S,
                                               float* __restrict__ out) {
    __shared__ float tile[64][65];
    int tid = threadIdx.x;
    int jb = blockIdx.z * N_ + blockIdx.x * 64;
    int o0 = blockIdx.y * 64;

    int r = tid >> 2, cq = (tid & 3) * 16;
    uint4 v = *(const uint4*)&T2[(size_t)(jb + r) * 256 + o0 + cq];
    ushort_t* pu = (ushort_t*)&v;
#pragma unroll
    for (int i = 0; i < 8; i++) {
        int o = o0 + cq + i;
        tile[r][cq + i] = fmaxf(A[o] * bf2f(pu[i]) + S[o], 0.f);
    }
    uint4 v2 = *(const uint4*)&T2[(size_t)(jb + r) * 256 + o0 + cq + 8];
    pu = (ushort_t*)&v2;
#pragma unroll
    for (int i = 0; i < 8; i++) {
        int o = o0 + cq + 8 + i;
        tile[r][cq + 8 + i] = fmaxf(A[o] * bf2f(pu[i]) + S[o], 0.f);
    }
    __syncthreads();

    int ro = tid >> 2, jq = (tid & 3) * 16;
    float* orow = out + ((size_t)blockIdx.z * 256 + o0 + ro) * N_ + blockIdx.x * 64 + jq;
#pragma unroll
    for (int h = 0; h < 4; h++) {
        float4 ov = {tile[jq + h * 4 + 0][ro], tile[jq + h * 4 + 1][ro],
                     tile[jq + h * 4 + 2][ro], tile[jq + h * 4 + 3][ro]};
        *(float4*)(orow + h * 4) = ov;
    }
}

// ---------------------------------------------------------------------------
extern "C" void kernel_launch(void* const* d_in, const int* in_sizes, int n_in,
                              void* d_out, int out_size, void* d_ws, size_t ws_size,
                              hipStream_t stream) {
    (void)in_sizes; (void)n_in; (void)out_size; (void)ws_size;
    const float* xyz1    = (const float*)d_in[0];
    const float* xyz2    = (const float*)d_in[1];
    const float* points1 = (const float*)d_in[2];
    const float* points2 = (const float*)d_in[3];
    const float* feature = (const float*)d_in[4];
    const float* W0 = (const float*)d_in[5];
    const float* b0 = (const float*)d_in[6];
    const float* g0 = (const float*)d_in[7];
    const float* be0 = (const float*)d_in[8];
    const float* W1 = (const float*)d_in[9];
    const float* b1 = (const float*)d_in[10];
    const float* g1 = (const float*)d_in[11];
    const float* be1 = (const float*)d_in[12];
    const float* W2 = (const float*)d_in[13];
    const float* b2 = (const float*)d_in[14];
    const float* g2 = (const float*)d_in[15];
    const float* be2 = (const float*)d_in[16];

    char* ws = (char*)d_ws;
    size_t off = 0;
    auto carve = [&](size_t bytes) { char* p = ws + off; off += (bytes + 255) & ~(size_t)255; return p; };

    ushort_t* XT  = (ushort_t*)carve((size_t)J_ * KP0 * 2);
    ushort_t* T0  = (ushort_t*)carve((size_t)J_ * 512 * 2);
    ushort_t* T1  = (ushort_t*)carve((size_t)J_ * 512 * 2);
    ushort_t* T2  = (ushort_t*)carve((size_t)J_ * 256 * 2);
    float*    p2t = (float*)carve((size_t)B_ * S_ * D2_ * 4);
    float*    nnp = (float*)carve((size_t)J_ * NE * 8 * 4);
    ushort_t* Wb0 = (ushort_t*)carve((size_t)512 * KP0 * 2);
    ushort_t* Wb1 = (ushort_t*)carve((size_t)512 * K12 * 2);
    ushort_t* Wb2 = (ushort_t*)carve((size_t)256 * K12 * 2);
    float*    pS  = (float*)carve((size_t)NJB * 512 * 4);   // per-block partial sums
    float*    pQ  = (float*)carve((size_t)NJB * 512 * 4);   // per-block partial sumsq
    float*    af  = (float*)carve(2560 * 4);
    float *A0 = af, *S0 = af + 512, *A1 = af + 1024, *S1 = af + 1536, *A2 = af + 2048, *S2 = af + 2304;

    k_prep_w<<<dim3((512 * KP0 + 255) / 256), 256, 0, stream>>>(W0, Wb0, 512, CIN_, KP0);
    k_prep_w<<<dim3((512 * K12 + 255) / 256), 256, 0, stream>>>(W1, Wb1, 512, 512, K12);
    k_prep_w<<<dim3((512 * 256 + 255) / 256), 256, 0, stream>>>(W2, Wb2, 256, 512, K12);
    k_transpose_p2<<<dim3(S_ / 32, D2_ / 32, B_), dim3(32, 8), 0, stream>>>(points2, p2t);
    k_p1t<<<dim3(N_ / 32, B_), 256, 0, stream>>>(points1, XT);
    k_scan<<<dim3(J_ / 512, NE), 256, 0, stream>>>(xyz1, xyz2, feature, nnp);
    k_nn2<<<dim3(N_ / 4, B_), 256, 0, stream>>>(feature, p2t, nnp, XT);

    k_gemm<<<dim3(256 * 4), 256, 0, stream>>>(XT, Wb0, b0, T0, pS, pQ, KP0, 512);
    k_affine<<<dim3(512 / 16), 256, 0, stream>>>(pS, pQ, g0, be0, A0, S0, 512);
    k_norm<<<dim3((int)((size_t)J_ * 512 / 8 / 256)), 256, 0, stream>>>(T0, A0, S0);

    k_gemm<<<dim3(256 * 4), 256, 0, stream>>>(T0, Wb1, b1, T1, pS, pQ, K12, 512);
    k_affine<<<dim3(512 / 16), 256, 0, stream>>>(pS, pQ, g1, be1, A1, S1, 512);
    k_norm<<<dim3((int)((size_t)J_ * 512 / 8 / 256)), 256, 0, stream>>>(T1, A1, S1);

    k_gemm<<<dim3(256 * 2), 256, 0, stream>>>(T1, Wb2, b2, T2, pS, pQ, K12, 256);
    k_affine<<<dim3(256 / 16), 256, 0, stream>>>(pS, pQ, g2, be2, A2, S2, 256);

    k_final<<<dim3(N_ / 64, 4, B_), 256, 0, stream>>>(T2, A2, S2, (float*)d_out);
}

// Round 14
// 183.414 us; speedup vs baseline: 1.3422x; 1.0474x over previous
//
#include <hip/hip_runtime.h>

#define B_   8
#define N_   4096
#define S_   1024
#define M_   2048
#define D1_  128
#define D2_  256
#define CIN_ 388
#define KP0  416          // K of layer0, padded to 13*32
#define K12  512          // K of layers 1,2
#define J_   (B_ * N_)    // 32768
#define NE   16           // candidate splits
#define SS   (S_ / NE)    // 64 candidates per chunk
#define MM   (M_ / NE)    // 128 keypoints per chunk
#define NJB  128          // j-blocks per GEMM (J/256)
#define BN_EPS 1e-5f

typedef __bf16 bf16x8 __attribute__((ext_vector_type(8)));
typedef float  f32x4  __attribute__((ext_vector_type(4)));
typedef unsigned short ushort_t;

__device__ __forceinline__ float mulrn(float a, float b) { return __fmul_rn(a, b); }
__device__ __forceinline__ float addrn(float a, float b) { return __fadd_rn(a, b); }
__device__ __forceinline__ float subrn(float a, float b) { return __fsub_rn(a, b); }
__device__ __forceinline__ float norm3(float x, float y, float z) {
    return addrn(addrn(mulrn(x, x), mulrn(y, y)), mulrn(z, z));
}
__device__ __forceinline__ ushort_t f2bf(float f) {  // RNE
    unsigned int u = __float_as_uint(f);
    return (ushort_t)((u + 0x7FFFu + ((u >> 16) & 1u)) >> 16);
}
__device__ __forceinline__ float bf2f(ushort_t u) {
    return __uint_as_float(((unsigned int)u) << 16);
}
// lexicographic (d, idx) compare — reproduces stable top-k tie-breaking
__device__ __forceinline__ bool plt(float da, int ia, float db, int ib) {
    return (da < db) || (da == db && ia < ib);
}

// ---------------------------------------------------------------------------
// points2 [B][D2][S] -> p2t [B][S][D2]  (fp32, feeds exact interp math)
__global__ __launch_bounds__(256) void k_transpose_p2(const float* __restrict__ p2,
                                                      float* __restrict__ p2t) {
    __shared__ float tile[32][33];
    int b = blockIdx.z;
    int s0 = blockIdx.x * 32, c0 = blockIdx.y * 32;
    int tx = threadIdx.x, ty = threadIdx.y;  // 32 x 8
#pragma unroll
    for (int i = 0; i < 4; i++)
        tile[ty + i * 8][tx] = p2[(size_t)b * D2_ * S_ + (size_t)(c0 + ty + i * 8) * S_ + s0 + tx];
    __syncthreads();
#pragma unroll
    for (int i = 0; i < 4; i++)
        p2t[(size_t)b * S_ * D2_ + (size_t)(s0 + ty + i * 8) * D2_ + c0 + tx] = tile[tx][ty + i * 8];
}

// ---------------------------------------------------------------------------
// W [O][C] fp32 -> Wb [O][Kp] bf16, zero-padded cols (already k-contiguous)
__global__ __launch_bounds__(256) void k_prep_w(const float* __restrict__ W,
                                                ushort_t* __restrict__ Wb, int O, int C, int Kp) {
    int i = blockIdx.x * 256 + threadIdx.x;
    if (i >= O * Kp) return;
    int o = i / Kp, k = i - o * Kp;
    Wb[i] = (k < C) ? f2bf(W[(size_t)o * C + k]) : (ushort_t)0;
}

// ---------------------------------------------------------------------------
// points1 [B][D1][N] fp32 -> XT[j][0:128] bf16 (LDS tile transpose)
__global__ __launch_bounds__(256) void k_p1t(const float* __restrict__ p1,
                                             ushort_t* __restrict__ XT) {
    __shared__ ushort_t tile[32][132];
    int b = blockIdx.y;
    int n0 = blockIdx.x * 32;
    int t = threadIdx.x;

    {
        int nl = t & 31, cq = t >> 5;
#pragma unroll
        for (int k = 0; k < 16; k++) {
            int c = cq * 16 + k;
            tile[nl][c] = f2bf(p1[(size_t)b * D1_ * N_ + (size_t)c * N_ + n0 + nl]);
        }
    }
    __syncthreads();
    {
        int nl = t >> 3, sub = t & 7;
        size_t j = (size_t)b * N_ + n0 + nl;
#pragma unroll
        for (int k = 0; k < 4; k++) {
            int chunk = k * 8 + sub;
            *(uint2*)&XT[j * KP0 + chunk * 4] = *(const uint2*)&tile[nl][chunk * 4];
        }
    }
}

// ---------------------------------------------------------------------------
// Scan phase: TWO queries per thread (shared candidate reads, 2 independent
// dep chains), one candidate-SIXTEENTH per block.
__global__ __launch_bounds__(256) void k_scan(const float* __restrict__ xyz1,
                                              const float* __restrict__ xyz2,
                                              const float* __restrict__ feature,
                                              float* __restrict__ outp) {
    __shared__ float4 sL[SS];
    __shared__ float4 fL[MM];
    int tid = threadIdx.x;
    int e = blockIdx.y;
    int b = blockIdx.x >> 3;           // 8 blocks.x per batch (4096/512)
    int jA = blockIdx.x * 512 + tid;   // query A
    int jB = jA + 256;                 // query B
    int nA = jA & (N_ - 1);
    int nB = nA + 256;

    for (int i = tid; i < SS + MM; i += 256) {
        if (i < SS) {
            int s = e * SS + i;
            float x = xyz2[(size_t)b * 3 * S_ + s];
            float y = xyz2[(size_t)b * 3 * S_ + S_ + s];
            float z = xyz2[(size_t)b * 3 * S_ + 2 * S_ + s];
            sL[i] = make_float4(x, y, z, norm3(x, y, z));
        } else {
            int m = e * MM + (i - SS);
            float4 f = *(const float4*)(feature + (size_t)b * M_ * 4 + (size_t)m * 4);
            fL[i - SS] = make_float4(f.y, f.z, f.w, norm3(f.y, f.z, f.w));
        }
    }
    __syncthreads();

    const float* xb = xyz1 + (size_t)b * 3 * N_;
    float qxA = xb[nA], qyA = xb[N_ + nA], qzA = xb[2 * N_ + nA];
    float qxB = xb[nB], qyB = xb[N_ + nB], qzB = xb[2 * N_ + nB];
    float qnA = norm3(qxA, qyA, qzA);
    float qnB = norm3(qxB, qyB, qzB);

    float d0A = 1e30f, d1A = 1e30f, d2A = 1e30f;
    float d0B = 1e30f, d1B = 1e30f, d2B = 1e30f;
    int i0A = 0, i1A = 0, i2A = 0, i0B = 0, i1B = 0, i2B = 0;
#pragma unroll 4
    for (int i = 0; i < SS; i++) {
        float4 c = sL[i];
        int s = e * SS + i;
        float dotA = addrn(addrn(mulrn(qxA, c.x), mulrn(qyA, c.y)), mulrn(qzA, c.z));
        float dA = subrn(addrn(qnA, c.w), mulrn(2.0f, dotA));
        float dotB = addrn(addrn(mulrn(qxB, c.x), mulrn(qyB, c.y)), mulrn(qzB, c.z));
        float dB = subrn(addrn(qnB, c.w), mulrn(2.0f, dotB));
        {
            bool l0 = dA < d0A, l1 = dA < d1A, l2 = dA < d2A;
            i2A = l1 ? i1A : (l2 ? s : i2A);
            i1A = l0 ? i0A : (l1 ? s : i1A);
            i0A = l0 ? s : i0A;
            d2A = fminf(fmaxf(dA, d1A), d2A);
            d1A = fminf(fmaxf(dA, d0A), d1A);
            d0A = fminf(dA, d0A);
        }
        {
            bool l0 = dB < d0B, l1 = dB < d1B, l2 = dB < d2B;
            i2B = l1 ? i1B : (l2 ? s : i2B);
            i1B = l0 ? i0B : (l1 ? s : i1B);
            i0B = l0 ? s : i0B;
            d2B = fminf(fmaxf(dB, d1B), d2B);
            d1B = fminf(fmaxf(dB, d0B), d1B);
            d0B = fminf(dB, d0B);
        }
    }

    float dmA = 1e30f, dmB = 1e30f;
    int imA = 0, imB = 0;
#pragma unroll 4
    for (int i = 0; i < MM; i++) {
        float4 c = fL[i];
        int m = e * MM + i;
        float dotA = addrn(addrn(mulrn(qxA, c.x), mulrn(qyA, c.y)), mulrn(qzA, c.z));
        float dA = subrn(addrn(qnA, c.w), mulrn(2.0f, dotA));
        float dotB = addrn(addrn(mulrn(qxB, c.x), mulrn(qyB, c.y)), mulrn(qzB, c.z));
        float dB = subrn(addrn(qnB, c.w), mulrn(2.0f, dotB));
        imA = (dA < dmA) ? m : imA;
        dmA = fminf(dA, dmA);
        imB = (dB < dmB) ? m : imB;
        dmB = fminf(dB, dmB);
    }

    {
        float* o = outp + ((size_t)jA * NE + e) * 8;
        float4 v0 = {d0A, d1A, d2A, dmA};
        float4 v1 = {__int_as_float(i0A), __int_as_float(i1A), __int_as_float(i2A), __int_as_float(imA)};
        *(float4*)o = v0;
        *(float4*)(o + 4) = v1;
    }
    {
        float* o = outp + ((size_t)jB * NE + e) * 8;
        float4 v0 = {d0B, d1B, d2B, dmB};
        float4 v1 = {__int_as_float(i0B), __int_as_float(i1B), __int_as_float(i2B), __int_as_float(imB)};
        *(float4*)o = v0;
        *(float4*)(o + 4) = v1;
    }
}

// ---------------------------------------------------------------------------
// Merge + assembly: one WAVE per query; 4-step lexicographic butterfly merge
// over 16 partials (same verified network).
__global__ __launch_bounds__(256) void k_nn2(const float* __restrict__ feature,
                                             const float* __restrict__ p2t,
                                             const float* __restrict__ outp,
                                             ushort_t* __restrict__ XT) {
    int bq = blockIdx.y;
    int wid = threadIdx.x >> 6;
    int l = threadIdx.x & 63;
    int n = blockIdx.x * 4 + wid;
    size_t j = (size_t)bq * N_ + n;
    const float* fb = feature + (size_t)bq * M_ * 4;

    float d0 = 1e30f, d1 = 1e30f, d2 = 1e30f, dm = 1e30f;
    int i0 = 0, i1 = 0, i2 = 0, im = 0;
    if (l < NE) {
        const float* o = outp + (j * NE + l) * 8;
        float4 a = *(const float4*)o;
        float4 bi = *(const float4*)(o + 4);
        d0 = a.x; d1 = a.y; d2 = a.z; dm = a.w;
        i0 = __float_as_int(bi.x); i1 = __float_as_int(bi.y);
        i2 = __float_as_int(bi.z); im = __float_as_int(bi.w);
    }

#pragma unroll
    for (int off = 1; off < NE; off <<= 1) {
        float e0 = __shfl_xor(d0, off), e1 = __shfl_xor(d1, off), e2 = __shfl_xor(d2, off);
        int   f0 = __shfl_xor(i0, off), f1 = __shfl_xor(i1, off), f2 = __shfl_xor(i2, off);
        bool c0 = plt(e0, f0, d0, i0);
        float m0d = c0 ? e0 : d0; int m0i = c0 ? f0 : i0;
        float x0d = c0 ? d0 : e0; int x0i = c0 ? i0 : f0;
        bool c1 = plt(e1, f1, d1, i1);
        float n1d = c1 ? e1 : d1; int n1i = c1 ? f1 : i1;
        float z1d = c1 ? d1 : e1; int z1i = c1 ? i1 : f1;
        bool c2 = plt(e2, f2, d2, i2);
        float w2d = c2 ? e2 : d2; int w2i = c2 ? f2 : i2;
        bool c3 = plt(n1d, n1i, x0d, x0i);
        float r1d = c3 ? n1d : x0d; int r1i = c3 ? n1i : x0i;
        float t2d = c3 ? x0d : n1d; int t2i = c3 ? x0i : n1i;
        bool c4 = plt(t2d, t2i, z1d, z1i);
        float u2d = c4 ? t2d : z1d; int u2i = c4 ? t2i : z1i;
        bool c5 = plt(w2d, w2i, u2d, u2i);
        float r2d = c5 ? w2d : u2d; int r2i = c5 ? w2i : u2i;
        d0 = m0d; i0 = m0i; d1 = r1d; i1 = r1i; d2 = r2d; i2 = r2i;

        float ed = __shfl_xor(dm, off); int ei = __shfl_xor(im, off);
        if (plt(ed, ei, dm, im)) { dm = ed; im = ei; }
    }

    d0 = __shfl(d0, 0); d1 = __shfl(d1, 0); d2 = __shfl(d2, 0);
    i0 = __shfl(i0, 0); i1 = __shfl(i1, 0); i2 = __shfl(i2, 0);
    im = __shfl(im, 0);

    float w0 = 1.0f / addrn(d0, 1e-8f);
    float w1 = 1.0f / addrn(d1, 1e-8f);
    float w2 = 1.0f / addrn(d2, 1e-8f);
    float wsum = addrn(addrn(w0, w1), w2);
    w0 = w0 / wsum; w1 = w1 / wsum; w2 = w2 / wsum;

    ushort_t* xr = XT + j * KP0;
    const float* r0 = p2t + (size_t)bq * S_ * D2_ + (size_t)i0 * D2_;
    const float* r1 = p2t + (size_t)bq * S_ * D2_ + (size_t)i1 * D2_;
    const float* r2 = p2t + (size_t)bq * S_ * D2_ + (size_t)i2 * D2_;
    {
        int c = l * 4;
        float4 a = *(const float4*)(r0 + c);
        float4 bb = *(const float4*)(r1 + c);
        float4 cc = *(const float4*)(r2 + c);
        ushort_t tmp[4];
        tmp[0] = f2bf(addrn(addrn(mulrn(a.x, w0), mulrn(bb.x, w1)), mulrn(cc.x, w2)));
        tmp[1] = f2bf(addrn(addrn(mulrn(a.y, w0), mulrn(bb.y, w1)), mulrn(cc.y, w2)));
        tmp[2] = f2bf(addrn(addrn(mulrn(a.z, w0), mulrn(bb.z, w1)), mulrn(cc.z, w2)));
        tmp[3] = f2bf(addrn(addrn(mulrn(a.w, w0), mulrn(bb.w, w1)), mulrn(cc.w, w2)));
        *(uint2*)&xr[D1_ + c] = *(uint2*)tmp;
    }
    if (l < 8) {
        uint2 v = {0u, 0u};
        if (l == 0) {
            float4 nf = *(const float4*)(fb + (size_t)im * 4);
            ushort_t tmp[4] = {f2bf(nf.x), f2bf(nf.y), f2bf(nf.z), f2bf(nf.w)};
            v = *(uint2*)tmp;
        }
        *(uint2*)&xr[384 + l * 4] = v;
    }
}

// ---------------------------------------------------------------------------
// bf16 MFMA GEMM, BM=256 x BN=128, 512 threads (8 waves: 4m x 2n).
// Per-wave inner loop identical to the proven 128^2 version (8 ds_read_b128 +
// 16 MFMA per K-step, same swizzle). Triple-buffered LDS (24KB/buf), prefetch
// distance 2, counted s_waitcnt vmcnt(3) (stage = 3 loads/thread: 2 X + 1 W).
// Grid = 128 jb x (Nout/128) ob -> 512 blocks = exactly 2/CU (no tail round).
// BN stats -> per-block partials (no atomics). Coalesced C-write via LDS
// bounce [256][136]. XCD-aware 1-D swizzle.
__global__ __launch_bounds__(512) void k_gemm(const ushort_t* __restrict__ Xb,
                                              const ushort_t* __restrict__ Wb,
                                              const float* __restrict__ bias,
                                              ushort_t* __restrict__ T,
                                              float* __restrict__ psumS,
                                              float* __restrict__ psumQ,
                                              int Kt, int Nout) {
    // 3 buffers x 24576 B (X 16KB | W 8KB) = 73728 B; stats 4 KB after.
    __shared__ __align__(16) char smem[77824];
    ushort_t* cb = (ushort_t*)smem;                    // bounce: 256*136*2 = 69632 B
    float* redS = (float*)(smem + 73728);              // [128][4] = 2 KB
    float* redQ = (float*)(smem + 75776);              // [128][4] = 2 KB

    int tid = threadIdx.x;
    int l = tid & 63;
    int w = tid >> 6;                 // 0..7
    int wr = w >> 1, wc = w & 1;      // 4 m-waves x 2 n-waves

    // XCD-aware bijective swizzle (grid = 128 * nOB blocks, 1-D)
    int bid = blockIdx.x;
    int jb = (bid & 7) + (((bid >> 3) & 15) << 3);   // 0..127
    int ob = bid >> 7;
    int j0 = jb * 256, o0 = ob * 128;

    f32x4 acc[4][4] = {};
    int nt = Kt >> 5;

    auto stage = [&](int buf, int kt) {
        int k0 = kt << 5;
        ushort_t* base = (ushort_t*)(smem + buf * 24576);
        // X: 256 rows x 4 chunks = 1024 slots, 2 per thread
#pragma unroll
        for (int e = 0; e < 2; ++e) {
            int i = e * 512 + tid;
            int row = i >> 2;
            int g = (i & 3) ^ ((row >> 1) & 3);   // pre-swizzled source chunk
            const ushort_t* ga = Xb + (size_t)(j0 + row) * Kt + k0 + g * 8;
            __builtin_amdgcn_global_load_lds(
                (const __attribute__((address_space(1))) void*)ga,
                (__attribute__((address_space(3))) void*)&base[i * 8], 16, 0, 0);
        }
        // W: 128 rows x 4 chunks = 512 slots, 1 per thread
        {
            int i = tid;
            int row = i >> 2;
            int g = (i & 3) ^ ((row >> 1) & 3);
            const ushort_t* gb = Wb + (size_t)(o0 + row) * Kt + k0 + g * 8;
            __builtin_amdgcn_global_load_lds(
                (const __attribute__((address_space(1))) void*)gb,
                (__attribute__((address_space(3))) void*)&base[8192 + i * 8], 16, 0, 0);
        }
    };

    // prologue: 2 tiles in flight, wait only the first (3 newest may fly)
    stage(0, 0);
    stage(1, 1);
    asm volatile("s_waitcnt vmcnt(3)" ::: "memory");
    __builtin_amdgcn_s_barrier();

    for (int t = 0; t < nt; ++t) {
        if (t + 2 < nt) stage((t + 2) % 3, t + 2);

        ushort_t* base = (ushort_t*)(smem + (t % 3) * 24576);
        bf16x8 av[4], bv[4];
#pragma unroll
        for (int mi = 0; mi < 4; ++mi) {
            int r = wr * 64 + mi * 16 + (l & 15);
            int sl = (l >> 4) ^ ((r >> 1) & 3);
            av[mi] = *(const bf16x8*)&base[r * 32 + sl * 8];
        }
#pragma unroll
        for (int ni = 0; ni < 4; ++ni) {
            int r = wc * 64 + ni * 16 + (l & 15);
            int sl = (l >> 4) ^ ((r >> 1) & 3);
            bv[ni] = *(const bf16x8*)&base[8192 + r * 32 + sl * 8];
        }
#pragma unroll
        for (int mi = 0; mi < 4; ++mi)
#pragma unroll
            for (int ni = 0; ni < 4; ++ni)
                acc[mi][ni] = __builtin_amdgcn_mfma_f32_16x16x32_bf16(av[mi], bv[ni],
                                                                      acc[mi][ni], 0, 0, 0);
        // need stage(t+1) complete; stage(t+2)'s 3 loads may stay in flight.
        if (t + 2 < nt)      asm volatile("s_waitcnt vmcnt(3)" ::: "memory");
        else if (t + 1 < nt) asm volatile("s_waitcnt vmcnt(0)" ::: "memory");
        __builtin_amdgcn_s_barrier();
    }

    // ---- epilogue: stats from regs + bounce acc -> LDS -> coalesced stores
    float csum[4], csq[4];
#pragma unroll
    for (int ni = 0; ni < 4; ++ni) { csum[ni] = 0.f; csq[ni] = 0.f; }

#pragma unroll
    for (int ni = 0; ni < 4; ++ni) {
        int oc = wc * 64 + ni * 16 + (l & 15);
        float bi = bias[o0 + oc];
#pragma unroll
        for (int mi = 0; mi < 4; ++mi) {
            int jr = wr * 64 + mi * 16 + (l >> 4) * 4;
#pragma unroll
            for (int r = 0; r < 4; ++r) {
                float v = acc[mi][ni][r] + bi;
                csum[ni] += v;
                csq[ni] += v * v;
                cb[(jr + r) * 136 + oc] = f2bf(v);
            }
        }
    }

#pragma unroll
    for (int ni = 0; ni < 4; ++ni) {
        float s = csum[ni], q = csq[ni];
        s += __shfl_xor(s, 16); s += __shfl_xor(s, 32);
        q += __shfl_xor(q, 16); q += __shfl_xor(q, 32);
        if ((l & 48) == 0) {  // lanes 0..15: column sums for this wave's 64 rows
            int oc = wc * 64 + ni * 16 + (l & 15);
            redS[oc * 4 + wr] = s;
            redQ[oc * 4 + wr] = q;
        }
    }
    __syncthreads();

    if (tid < 128) {
        psumS[(size_t)jb * Nout + o0 + tid] =
            (redS[tid * 4] + redS[tid * 4 + 1]) + (redS[tid * 4 + 2] + redS[tid * 4 + 3]);
        psumQ[(size_t)jb * Nout + o0 + tid] =
            (redQ[tid * 4] + redQ[tid * 4 + 1]) + (redQ[tid * 4 + 2] + redQ[tid * 4 + 3]);
    }
#pragma unroll
    for (int p = 0; p < 8; ++p) {
        int idx = p * 512 + tid;
        int jr = idx >> 4, oc8 = (idx & 15) * 8;
        uint4 v = *(const uint4*)&cb[jr * 136 + oc8];
        *(uint4*)&T[(size_t)(j0 + jr) * Nout + o0 + oc8] = v;
    }
}

// ---------------------------------------------------------------------------
// Hierarchical reduce of per-block partials -> BN affine (a, s): y = a*x + s.
// 16 channels x 16 partial-chunks (8 rows each, NJB=128).
__global__ __launch_bounds__(256) void k_affine(const float* __restrict__ pS,
                                                const float* __restrict__ pQ,
                                                const float* __restrict__ g,
                                                const float* __restrict__ be,
                                                float* __restrict__ A,
                                                float* __restrict__ S, int C) {
    __shared__ float rs[16][17], rq[16][17];
    int t = threadIdx.x;
    int ch = t & 15, part = t >> 4;      // 16 x 16
    int o = blockIdx.x * 16 + ch;
    float s = 0.f, q = 0.f;
#pragma unroll
    for (int k = 0; k < 8; k++) {
        int jb = part * 8 + k;
        s += pS[(size_t)jb * C + o];
        q += pQ[(size_t)jb * C + o];
    }
    rs[part][ch] = s; rq[part][ch] = q;
    __syncthreads();
    if (t < 16) {
        float ss = 0.f, qq = 0.f;
        for (int p = 0; p < 16; p++) { ss += rs[p][t]; qq += rq[p][t]; }
        int oo = blockIdx.x * 16 + t;
        float mean = ss / (float)J_;
        float var = qq / (float)J_ - mean * mean;
        float a = g[oo] * rsqrtf(var + BN_EPS);
        A[oo] = a;
        S[oo] = be[oo] - a * mean;
    }
}

// ---------------------------------------------------------------------------
// In-place BN+ReLU on T [J][512] bf16 (channel = col = idx & 511)
__global__ __launch_bounds__(256) void k_norm(ushort_t* __restrict__ T,
                                              const float* __restrict__ A,
                                              const float* __restrict__ S) {
    size_t idx = ((size_t)blockIdx.x * 256 + threadIdx.x) * 8;
    int o = (int)(idx & 511);
    uint4 v = *(uint4*)&T[idx];
    ushort_t* pu = (ushort_t*)&v;
#pragma unroll
    for (int i = 0; i < 8; i++) {
        float f = bf2f(pu[i]);
        f = fmaxf(A[o + i] * f + S[o + i], 0.f);
        pu[i] = f2bf(f);
    }
    *(uint4*)&T[idx] = v;
}

// ---------------------------------------------------------------------------
// T2 [J][256] bf16 + BN affine + ReLU -> out [B][256][N] fp32 (transpose)
__global__ __launch_bounds__(256) void k_final(const ushort_t* __restrict__ T2,
                                               const float* __restrict__ A,
                                               const float* __restrict__ S,
                                               float* __restrict__ out) {
    __shared__ float tile[64][65];
    int tid = threadIdx.x;
    int jb = blockIdx.z * N_ + blockIdx.x * 64;
    int o0 = blockIdx.y * 64;

    int r = tid >> 2, cq = (tid & 3) * 16;
    uint4 v = *(const uint4*)&T2[(size_t)(jb + r) * 256 + o0 + cq];
    ushort_t* pu = (ushort_t*)&v;
#pragma unroll
    for (int i = 0; i < 8; i++) {
        int o = o0 + cq + i;
        tile[r][cq + i] = fmaxf(A[o] * bf2f(pu[i]) + S[o], 0.f);
    }
    uint4 v2 = *(const uint4*)&T2[(size_t)(jb + r) * 256 + o0 + cq + 8];
    pu = (ushort_t*)&v2;
#pragma unroll
    for (int i = 0; i < 8; i++) {
        int o = o0 + cq + 8 + i;
        tile[r][cq + 8 + i] = fmaxf(A[o] * bf2f(pu[i]) + S[o], 0.f);
    }
    __syncthreads();

    int ro = tid >> 2, jq = (tid & 3) * 16;
    float* orow = out + ((size_t)blockIdx.z * 256 + o0 + ro) * N_ + blockIdx.x * 64 + jq;
#pragma unroll
    for (int h = 0; h < 4; h++) {
        float4 ov = {tile[jq + h * 4 + 0][ro], tile[jq + h * 4 + 1][ro],
                     tile[jq + h * 4 + 2][ro], tile[jq + h * 4 + 3][ro]};
        *(float4*)(orow + h * 4) = ov;
    }
}

// ---------------------------------------------------------------------------
extern "C" void kernel_launch(void* const* d_in, const int* in_sizes, int n_in,
                              void* d_out, int out_size, void* d_ws, size_t ws_size,
                              hipStream_t stream) {
    (void)in_sizes; (void)n_in; (void)out_size; (void)ws_size;
    const float* xyz1    = (const float*)d_in[0];
    const float* xyz2    = (const float*)d_in[1];
    const float* points1 = (const float*)d_in[2];
    const float* points2 = (const float*)d_in[3];
    const float* feature = (const float*)d_in[4];
    const float* W0 = (const float*)d_in[5];
    const float* b0 = (const float*)d_in[6];
    const float* g0 = (const float*)d_in[7];
    const float* be0 = (const float*)d_in[8];
    const float* W1 = (const float*)d_in[9];
    const float* b1 = (const float*)d_in[10];
    const float* g1 = (const float*)d_in[11];
    const float* be1 = (const float*)d_in[12];
    const float* W2 = (const float*)d_in[13];
    const float* b2 = (const float*)d_in[14];
    const float* g2 = (const float*)d_in[15];
    const float* be2 = (const float*)d_in[16];

    char* ws = (char*)d_ws;
    size_t off = 0;
    auto carve = [&](size_t bytes) { char* p = ws + off; off += (bytes + 255) & ~(size_t)255; return p; };

    ushort_t* XT  = (ushort_t*)carve((size_t)J_ * KP0 * 2);
    ushort_t* T0  = (ushort_t*)carve((size_t)J_ * 512 * 2);
    ushort_t* T1  = (ushort_t*)carve((size_t)J_ * 512 * 2);
    ushort_t* T2  = (ushort_t*)carve((size_t)J_ * 256 * 2);
    float*    p2t = (float*)carve((size_t)B_ * S_ * D2_ * 4);
    float*    nnp = (float*)carve((size_t)J_ * NE * 8 * 4);
    ushort_t* Wb0 = (ushort_t*)carve((size_t)512 * KP0 * 2);
    ushort_t* Wb1 = (ushort_t*)carve((size_t)512 * K12 * 2);
    ushort_t* Wb2 = (ushort_t*)carve((size_t)256 * K12 * 2);
    float*    pS  = (float*)carve((size_t)NJB * 512 * 4);   // per-block partial sums
    float*    pQ  = (float*)carve((size_t)NJB * 512 * 4);   // per-block partial sumsq
    float*    af  = (float*)carve(2560 * 4);
    float *A0 = af, *S0 = af + 512, *A1 = af + 1024, *S1 = af + 1536, *A2 = af + 2048, *S2 = af + 2304;

    k_prep_w<<<dim3((512 * KP0 + 255) / 256), 256, 0, stream>>>(W0, Wb0, 512, CIN_, KP0);
    k_prep_w<<<dim3((512 * K12 + 255) / 256), 256, 0, stream>>>(W1, Wb1, 512, 512, K12);
    k_prep_w<<<dim3((512 * 256 + 255) / 256), 256, 0, stream>>>(W2, Wb2, 256, 512, K12);
    k_transpose_p2<<<dim3(S_ / 32, D2_ / 32, B_), dim3(32, 8), 0, stream>>>(points2, p2t);
    k_p1t<<<dim3(N_ / 32, B_), 256, 0, stream>>>(points1, XT);
    k_scan<<<dim3(J_ / 512, NE), 256, 0, stream>>>(xyz1, xyz2, feature, nnp);
    k_nn2<<<dim3(N_ / 4, B_), 256, 0, stream>>>(feature, p2t, nnp, XT);

    k_gemm<<<dim3(NJB * 4), 512, 0, stream>>>(XT, Wb0, b0, T0, pS, pQ, KP0, 512);
    k_affine<<<dim3(512 / 16), 256, 0, stream>>>(pS, pQ, g0, be0, A0, S0, 512);
    k_norm<<<dim3((int)((size_t)J_ * 512 / 8 / 256)), 256, 0, stream>>>(T0, A0, S0);

    k_gemm<<<dim3(NJB * 4), 512, 0, stream>>>(T0, Wb1, b1, T1, pS, pQ, K12, 512);
    k_affine<<<dim3(512 / 16), 256, 0, stream>>>(pS, pQ, g1, be1, A1, S1, 512);
    k_norm<<<dim3((int)((size_t)J_ * 512 / 8 / 256)), 256, 0, stream>>>(T1, A1, S1);

    k_gemm<<<dim3(NJB * 2), 512, 0, stream>>>(T1, Wb2, b2, T2, pS, pQ, K12, 256);
    k_affine<<<dim3(256 / 16), 256, 0, stream>>>(pS, pQ, g2, be2, A2, S2, 256);

    k_final<<<dim3(N_ / 64, 4, B_), 256, 0, stream>>>(T2, A2, S2, (float*)d_out);
}